// Round 1
// baseline (614.398 us; speedup 1.0000x reference)
//
#include <hip/hip_runtime.h>

#define NCTX 3
#define B 8
#define CC 128
#define CF 256
#define H 64
#define W 64
#define HW 4096
#define YX 16384   // (2H)*(2W)

// workspace layout (float offsets)
#define WS_QT    0          // B*CC*HW = 4194304
#define WS_VALS  4194304    // B*CC*HW
#define WS_QB    8388608    // B*HW = 32768
#define WS_LM    8421376    // B*HW
#define WS_WFT   8454144    // CF*CC = 32768   [f][o]
#define WS_WKT   8486912    // CF*CC           [f][o]
#define WS_WQTT  8519680    // CF*CC           [f][c]
#define WS_WVT   8552448    // CF*9*CC = 294912  [(ci*3+kh)*3+kw][co]
#define WS_BQT   8847360    // CC
#define WS_WQB   8847488    // CF
#define WS_BQB   8847744    // 1

// ---------------- K0a: weight transposes ----------------
__global__ void k0a(const float* __restrict__ Wf, const float* __restrict__ Wk,
                    const float* __restrict__ Wv,
                    float* __restrict__ WfT, float* __restrict__ WkT,
                    float* __restrict__ WvT) {
    int i = blockIdx.x * 256 + threadIdx.x;
    if (i < 32768) {
        int f = i >> 7, o = i & 127;       // i = f*128 + o
        WfT[i] = Wf[o * 256 + f];
        WkT[i] = Wk[o * 256 + f];
    }
    for (int j = i; j < 294912; j += gridDim.x * 256) {
        int co = j & 127;
        int r  = j >> 7;                    // (ci*3+kh)*3+kw
        int kw = r % 3; int t2 = r / 3; int kh = t2 % 3; int ci = t2 / 3;
        WvT[j] = Wv[((co * 256 + ci) * 3 + kh) * 3 + kw];
    }
}

// ---------------- K0b: fused attention-key weights ----------------
// qt = (Wc^T Wf) @ ms + (Wc^T Wf_b)   ;  qb = (Wc_b^T Wf) @ ms + Wc_b.Wf_b
__global__ void k0b(const float* __restrict__ Wc_w, const float* __restrict__ Wc_b,
                    const float* __restrict__ Wf_w, const float* __restrict__ Wf_b,
                    float* __restrict__ WqtT, float* __restrict__ bqt,
                    float* __restrict__ wqb, float* __restrict__ bqb) {
    int i = blockIdx.x * 256 + threadIdx.x;
    if (i < 32768) {
        int f = i >> 7, c = i & 127;        // layout [f][c]
        float s = 0.f;
        for (int o = 0; o < 128; ++o) s += Wc_w[o * 128 + c] * Wf_w[o * 256 + f];
        WqtT[i] = s;
    } else if (i < 32896) {
        int c = i - 32768;
        float s = 0.f;
        for (int o = 0; o < 128; ++o) s += Wc_w[o * 128 + c] * Wf_b[o];
        bqt[c] = s;
    } else if (i < 33152) {
        int f = i - 32896;
        float s = 0.f;
        for (int o = 0; o < 128; ++o) s += Wc_b[o] * Wf_w[o * 256 + f];
        wqb[f] = s;
    } else if (i == 33152) {
        float s = 0.f;
        for (int o = 0; o < 128; ++o) s += Wc_b[o] * Wf_b[o];
        *bqb = s;
    }
}

// ---------------- K1: per-pixel qt, qb, logit_main ----------------
// block = 256 threads, 16 pixels (contiguous hw within one b)
__global__ __launch_bounds__(256) void k1(
    const float* __restrict__ ms,
    const float* __restrict__ WfT, const float* __restrict__ WkT,
    const float* __restrict__ WqtT,
    const float* __restrict__ Wf_b, const float* __restrict__ Wk_b,
    const float* __restrict__ bqt, const float* __restrict__ wqb,
    const float* __restrict__ bqb,
    float* __restrict__ qt, float* __restrict__ qb, float* __restrict__ lm) {
    __shared__ float Xs[256][16];
    __shared__ float qm[256][16];   // rows 0..127 = q, 128..255 = mkey
    int t = threadIdx.x;
    int blk = blockIdx.x;           // 2048 blocks
    int b = blk >> 8;
    int hw0 = (blk & 255) << 4;
    const float* msb = ms + (size_t)b * (CF * HW) + hw0;
    for (int l = t; l < 4096; l += 256) {
        int f = l >> 4, px = l & 15;
        Xs[f][px] = msb[f * HW + px];
    }
    __syncthreads();
    // phase A: q rows (t<128) and mkey rows (t>=128)
    {
        int row = t & 127;
        const float* WT = (t < 128) ? WfT : WkT;
        float acc[16];
#pragma unroll
        for (int px = 0; px < 16; ++px) acc[px] = 0.f;
        for (int f = 0; f < 256; ++f) {
            float wv = WT[f * 128 + row];
            const float4* xr = (const float4*)&Xs[f][0];
            float4 a0 = xr[0], a1 = xr[1], a2 = xr[2], a3 = xr[3];
            acc[0] += wv * a0.x; acc[1] += wv * a0.y; acc[2] += wv * a0.z; acc[3] += wv * a0.w;
            acc[4] += wv * a1.x; acc[5] += wv * a1.y; acc[6] += wv * a1.z; acc[7] += wv * a1.w;
            acc[8] += wv * a2.x; acc[9] += wv * a2.y; acc[10] += wv * a2.z; acc[11] += wv * a2.w;
            acc[12] += wv * a3.x; acc[13] += wv * a3.y; acc[14] += wv * a3.z; acc[15] += wv * a3.w;
        }
        float bias = (t < 128) ? Wf_b[row] : Wk_b[row];
#pragma unroll
        for (int px = 0; px < 16; ++px) qm[t][px] = acc[px] + bias;
    }
    __syncthreads();
    if (t < 128) {
        int c = t;
        float acc[16];
#pragma unroll
        for (int px = 0; px < 16; ++px) acc[px] = 0.f;
        for (int f = 0; f < 256; ++f) {
            float wv = WqtT[f * 128 + c];
            const float4* xr = (const float4*)&Xs[f][0];
            float4 a0 = xr[0], a1 = xr[1], a2 = xr[2], a3 = xr[3];
            acc[0] += wv * a0.x; acc[1] += wv * a0.y; acc[2] += wv * a0.z; acc[3] += wv * a0.w;
            acc[4] += wv * a1.x; acc[5] += wv * a1.y; acc[6] += wv * a1.z; acc[7] += wv * a1.w;
            acc[8] += wv * a2.x; acc[9] += wv * a2.y; acc[10] += wv * a2.z; acc[11] += wv * a2.w;
            acc[12] += wv * a3.x; acc[13] += wv * a3.y; acc[14] += wv * a3.z; acc[15] += wv * a3.w;
        }
        float bb = bqt[c];
        float* dst = qt + (size_t)b * (CC * HW) + c * HW + hw0;
#pragma unroll
        for (int px = 0; px < 16; ++px) dst[px] = acc[px] + bb;
    } else if (t < 144) {
        int px = t - 128;
        float s = 0.f;
        for (int c = 0; c < 128; ++c) s += qm[c][px] * qm[c + 128][px];
        lm[b * HW + hw0 + px] = s;
    } else if (t < 160) {
        int px = t - 144;
        float s = *bqb;
        for (int f = 0; f < 256; ++f) s += wqb[f] * Xs[f][px];
        qb[b * HW + hw0 + px] = s;
    }
}

// ---------------- K2: 3x3 conv (vals) ----------------
// block = 256 threads: 128 co x 32 pixels (one row segment)
__global__ __launch_bounds__(256) void k2(
    const float* __restrict__ ms, const float* __restrict__ WvT,
    const float* __restrict__ Wv_b, float* __restrict__ vals) {
    __shared__ float Xs[32][3][34];
    int t = threadIdx.x;
    int blk = blockIdx.x;       // 1024 = 8*64*2
    int b = blk >> 7;
    int h = (blk >> 1) & 63;
    int w0 = (blk & 1) * 32;
    int co = t & 127;
    int g = t >> 7;             // pixel group 0/1
    float acc[16];
#pragma unroll
    for (int px = 0; px < 16; ++px) acc[px] = 0.f;
    const float* msb = ms + (size_t)b * (CF * HW);
    for (int ci0 = 0; ci0 < 256; ci0 += 32) {
        __syncthreads();
        for (int l = t; l < 32 * 3 * 34; l += 256) {
            int ci = l / 102;
            int rem = l - ci * 102;
            int r = rem / 34;
            int cl = rem - r * 34;
            int y = h + r - 1;
            int x = w0 + cl - 1;
            float v = 0.f;
            if (y >= 0 && y < 64 && x >= 0 && x < 64)
                v = msb[(ci0 + ci) * HW + y * 64 + x];
            Xs[ci][r][cl] = v;
        }
        __syncthreads();
        for (int ci = 0; ci < 32; ++ci) {
#pragma unroll
            for (int kh = 0; kh < 3; ++kh) {
                const float* wp = WvT + (size_t)(((ci0 + ci) * 3 + kh) * 3) * 128 + co;
                float wv0 = wp[0], wv1 = wp[128], wv2 = wp[256];
#pragma unroll
                for (int px = 0; px < 16; ++px) {
                    float x0 = Xs[ci][kh][g * 16 + px];
                    float x1 = Xs[ci][kh][g * 16 + px + 1];
                    float x2 = Xs[ci][kh][g * 16 + px + 2];
                    acc[px] += wv0 * x0 + wv1 * x1 + wv2 * x2;
                }
            }
        }
    }
    float bias = Wv_b[co];
    float* dst = vals + (size_t)b * (CC * HW) + co * HW + h * 64 + w0 + g * 16;
#pragma unroll
    for (int px = 0; px < 16; ++px) dst[px] = acc[px] + bias;
}

// ---------------- K3: fused logits -> softmax -> combine ----------------
// block = 256 threads: (b, h, quarter of W) -> 16 main px, 2x32 ctx sub-px
__global__ __launch_bounds__(256) void k3(
    const float* __restrict__ ctx, const float* __restrict__ qt,
    const float* __restrict__ vals, const float* __restrict__ qb,
    const float* __restrict__ lm, float* __restrict__ out) {
    __shared__ float qtS[128][16];
    __shared__ float vS[128][16];
    __shared__ float ctxS[128][64];    // [c][i*32+s]
    __shared__ float part[64][4];
    __shared__ float logitsS[3][64];
    __shared__ float attnS[4][64];
    __shared__ float qbS[16], lmS[16];
    int t = threadIdx.x;
    int blk = blockIdx.x;              // 2048 = 8*64*4
    int b = blk >> 8;
    int h = (blk >> 2) & 63;
    int q0 = blk & 3;
    int p0 = q0 * 16;                  // main pixel base (w)
    int x0 = q0 * 32;                  // ctx col base
    for (int l = t; l < 2048; l += 256) {
        int c = l >> 4, p = l & 15;
        size_t off = (size_t)b * (CC * HW) + c * HW + h * 64 + p0 + p;
        qtS[c][p] = qt[off];
        vS[c][p]  = vals[off];
    }
    if (t < 16) {
        qbS[t] = qb[b * HW + h * 64 + p0 + t];
        lmS[t] = lm[b * HW + h * 64 + p0 + t];
    }
    // logits for each context
    for (int n = 0; n < 3; ++n) {
        __syncthreads();
        const float* cb = ctx + (size_t)(n * B + b) * CC * YX;
        for (int l = t; l < 8192; l += 256) {
            int c = l >> 6, r = l & 63;
            int i = r >> 5, s = r & 31;
            ctxS[c][r] = cb[(size_t)c * YX + (2 * h + i) * 128 + x0 + s];
        }
        __syncthreads();
        {
            int d = t >> 2, qq = t & 3;
            int s = d & 31;
            int p = s >> 1;
            float sum = 0.f;
            int cbase = qq * 32;
            for (int c = 0; c < 32; ++c)
                sum += ctxS[cbase + c][d] * qtS[cbase + c][p];
            part[d][qq] = sum;
        }
        __syncthreads();
        if (t < 64)
            logitsS[n][t] = part[t][0] + part[t][1] + part[t][2] + part[t][3]
                            + qbS[(t & 31) >> 1];
    }
    __syncthreads();
    if (t < 64) {
        int p = (t & 31) >> 1;
        float l0 = logitsS[0][t], l1 = logitsS[1][t], l2 = logitsS[2][t], l3 = lmS[p];
        float m = fmaxf(fmaxf(l0, l1), fmaxf(l2, l3));
        float e0 = __expf(l0 - m), e1 = __expf(l1 - m), e2 = __expf(l2 - m), e3 = __expf(l3 - m);
        float inv = 1.f / (e0 + e1 + e2 + e3);
        attnS[0][t] = e0 * inv; attnS[1][t] = e1 * inv;
        attnS[2][t] = e2 * inv; attnS[3][t] = e3 * inv;
    }
    __syncthreads();
    // combine
    int sp = t & 63;                   // i*32+s
    int i = sp >> 5, s = sp & 31, p = s >> 1;
    int ch = t >> 6;                   // c quarter
    float acc[32];
    float am = attnS[3][sp];
#pragma unroll
    for (int cc = 0; cc < 32; ++cc) acc[cc] = am * vS[ch * 32 + cc][p];
    for (int n = 0; n < 3; ++n) {
        __syncthreads();
        const float* cb = ctx + (size_t)(n * B + b) * CC * YX;
        for (int l = t; l < 8192; l += 256) {
            int c = l >> 6, r = l & 63;
            int ii = r >> 5, ss = r & 31;
            ctxS[c][r] = cb[(size_t)c * YX + (2 * h + ii) * 128 + x0 + ss];
        }
        __syncthreads();
        float an = attnS[n][sp];
#pragma unroll
        for (int cc = 0; cc < 32; ++cc) acc[cc] += an * ctxS[ch * 32 + cc][sp];
    }
#pragma unroll
    for (int cc = 0; cc < 32; ++cc) {
        int c = ch * 32 + cc;
        out[((size_t)b * CC + c) * YX + (2 * h + i) * 128 + x0 + s] = acc[cc];
    }
}

extern "C" void kernel_launch(void* const* d_in, const int* in_sizes, int n_in,
                              void* d_out, int out_size, void* d_ws, size_t ws_size,
                              hipStream_t stream) {
    const float* ctx  = (const float*)d_in[0];
    const float* ms   = (const float*)d_in[1];
    const float* Wc_w = (const float*)d_in[2];
    const float* Wc_b = (const float*)d_in[3];
    const float* Wf_w = (const float*)d_in[4];
    const float* Wf_b = (const float*)d_in[5];
    const float* Wk_w = (const float*)d_in[6];
    const float* Wk_b = (const float*)d_in[7];
    const float* Wv_w = (const float*)d_in[8];
    const float* Wv_b = (const float*)d_in[9];
    float* out = (float*)d_out;
    float* ws = (float*)d_ws;
    float* qt   = ws + WS_QT;
    float* vals = ws + WS_VALS;
    float* qb   = ws + WS_QB;
    float* lmp  = ws + WS_LM;
    float* WfT  = ws + WS_WFT;
    float* WkT  = ws + WS_WKT;
    float* WqtT = ws + WS_WQTT;
    float* WvT  = ws + WS_WVT;
    float* bqt  = ws + WS_BQT;
    float* wqb  = ws + WS_WQB;
    float* bqb  = ws + WS_BQB;

    hipLaunchKernelGGL(k0a, dim3(256), dim3(256), 0, stream, Wf_w, Wk_w, Wv_w, WfT, WkT, WvT);
    hipLaunchKernelGGL(k0b, dim3(130), dim3(256), 0, stream, Wc_w, Wc_b, Wf_w, Wf_b, WqtT, bqt, wqb, bqb);
    hipLaunchKernelGGL(k1, dim3(2048), dim3(256), 0, stream, ms, WfT, WkT, WqtT,
                       Wf_b, Wk_b, bqt, wqb, bqb, qt, qb, lmp);
    hipLaunchKernelGGL(k2, dim3(1024), dim3(256), 0, stream, ms, WvT, Wv_b, vals);
    hipLaunchKernelGGL(k3, dim3(2048), dim3(256), 0, stream, ctx, qt, vals, qb, lmp, out);
}

// Round 2
// 301.638 us; speedup vs baseline: 2.0369x; 2.0369x over previous
//
#include <hip/hip_runtime.h>

#define NCTX 3
#define B 8
#define CC 128
#define CF 256
#define H 64
#define W 64
#define HW 4096
#define YX 16384   // (2H)*(2W)

// workspace layout (float offsets)
#define WS_QT    0          // B*CC*HW = 4194304
#define WS_VALS  4194304    // B*CC*HW
#define WS_QB    8388608    // B*HW = 32768
#define WS_LM    8421376    // B*HW
#define WS_WFT   8454144    // CF*CC = 32768   [f][o]
#define WS_WKT   8486912    // CF*CC           [f][o]
#define WS_WQTT  8519680    // CF*CC           [f][c]
#define WS_BQT   8552448    // CC
#define WS_WQB   8552576    // CF
#define WS_BQB   8552832    // 1  (pad to 8552960)
#define WS_MSP   8552960    // bf16 msP: 8*66*32*66*8 = 8921088 ushorts = 4460544 floats
#define WS_WB    13013504   // bf16 Wb: 9*8*4*128*8 = 294912 ushorts = 147456 floats
#define MSP_USHORTS 8921088

typedef __attribute__((ext_vector_type(8))) short bf16x8;
typedef __attribute__((ext_vector_type(4))) float f32x4;
typedef __attribute__((ext_vector_type(8))) unsigned short u16x8;

__device__ __forceinline__ unsigned short f2b(float f) {
    union { float f; unsigned u; } c; c.f = f;
    unsigned u = c.u + 0x7FFFu + ((c.u >> 16) & 1u);
    return (unsigned short)(u >> 16);
}

// ---------------- K0a: weight transposes (fp32, for k1) ----------------
__global__ void k0a(const float* __restrict__ Wf, const float* __restrict__ Wk,
                    float* __restrict__ WfT, float* __restrict__ WkT) {
    int i = blockIdx.x * 256 + threadIdx.x;   // 32768 threads
    int f = i >> 7, o = i & 127;              // i = f*128 + o
    WfT[i] = Wf[o * 256 + f];
    WkT[i] = Wk[o * 256 + f];
}

// ---------------- K0b: fused attention-key weights ----------------
__global__ void k0b(const float* __restrict__ Wc_w, const float* __restrict__ Wc_b,
                    const float* __restrict__ Wf_w, const float* __restrict__ Wf_b,
                    float* __restrict__ WqtT, float* __restrict__ bqt,
                    float* __restrict__ wqb, float* __restrict__ bqb) {
    int i = blockIdx.x * 256 + threadIdx.x;
    if (i < 32768) {
        int f = i >> 7, c = i & 127;        // layout [f][c]
        float s = 0.f;
        for (int o = 0; o < 128; ++o) s += Wc_w[o * 128 + c] * Wf_w[o * 256 + f];
        WqtT[i] = s;
    } else if (i < 32896) {
        int c = i - 32768;
        float s = 0.f;
        for (int o = 0; o < 128; ++o) s += Wc_w[o * 128 + c] * Wf_b[o];
        bqt[c] = s;
    } else if (i < 33152) {
        int f = i - 32896;
        float s = 0.f;
        for (int o = 0; o < 128; ++o) s += Wc_b[o] * Wf_w[o * 256 + f];
        wqb[f] = s;
    } else if (i == 33152) {
        float s = 0.f;
        for (int o = 0; o < 128; ++o) s += Wc_b[o] * Wf_b[o];
        *bqb = s;
    }
}

// ---------------- K0c: conv weights -> bf16 Wb[khw][s][c4][co][8ci] ----------------
__global__ void k0c(const float* __restrict__ Wv, unsigned short* __restrict__ Wb) {
    int o = blockIdx.x * 256 + threadIdx.x;   // 294912 threads exactly
    int ci8 = o & 7;
    int co  = (o >> 3) & 127;
    int c4  = (o >> 10) & 3;
    int s   = (o >> 12) & 7;
    int khw = o >> 15;                        // [0,9)
    int ci  = s * 32 + c4 * 8 + ci8;
    int kh  = khw / 3, kw = khw - kh * 3;
    Wb[o] = f2b(Wv[((co * 256 + ci) * 3 + kh) * 3 + kw]);
}

// ---------------- K2p: ms -> padded, transposed bf16 msP[b][y66][g32][x66][8ci] ----
__global__ __launch_bounds__(256) void k2p(const float* __restrict__ ms,
                                           unsigned short* __restrict__ msP) {
    __shared__ float Ls[32][65];
    int t = threadIdx.x;
    int blk = blockIdx.x;          // 4096 = 8b * 64h * 8s
    int s = blk & 7;
    int h = (blk >> 3) & 63;
    int b = blk >> 9;
    const float* src = ms + ((size_t)b * 256 + s * 32) * HW + h * 64;
    for (int l = t; l < 2048; l += 256) {
        int ci = l >> 6, w = l & 63;
        Ls[ci][w] = src[ci * HW + w];
    }
    __syncthreads();
    int w = t & 63, gi = t >> 6;   // gi in [0,4)
    u16x8 v;
#pragma unroll
    for (int j = 0; j < 8; ++j) v[j] = f2b(Ls[gi * 8 + j][w]);
    size_t off = ((((size_t)b * 66 + (h + 1)) * 32) + (s * 4 + gi)) * 66 + (w + 1);
    *(u16x8*)&msP[off * 8] = v;
}

// ---------------- K2m: implicit-GEMM MFMA 3x3 conv ----------------
// grid 256 = 8b * 32hB; block 256 = 4 waves (2 co-halves x 2 rows)
__global__ __launch_bounds__(256, 1) void k2m(const unsigned short* __restrict__ msP,
                                              const unsigned short* __restrict__ Wb,
                                              const float* __restrict__ Wv_b,
                                              float* __restrict__ vals) {
    __shared__ unsigned short Bs[2][8448];   // [buf][(r*4+c4)*66 + x][8ci]
    __shared__ float biasS[128];
    int t = threadIdx.x;
    int lane = t & 63, wid = t >> 6;
    int wm = wid >> 1, wn = wid & 1;
    int b = blockIdx.x >> 5, hB = blockIdx.x & 31;
    int c4l = lane >> 4, lrow = lane & 15;
    if (t < 128) biasS[t] = Wv_b[t];

    f32x4 acc[4][4];
#pragma unroll
    for (int mf = 0; mf < 4; ++mf)
#pragma unroll
        for (int nf = 0; nf < 4; ++nf) acc[mf][nf] = (f32x4){0.f, 0.f, 0.f, 0.f};

    const bf16x8* Wbp = (const bf16x8*)Wb;

#define STAGE(bufv, sv) do {                                                        \
    for (int iter = 0; iter < 5; ++iter) {                                          \
        int q0 = iter * 256 + (wid << 6);                                           \
        int q = q0 + lane;                                                          \
        if (q < 1056) {                                                             \
            int r = q / 264; int rem = q - r * 264;                                 \
            int c4 = rem / 66; int x = rem - c4 * 66;                               \
            int y = 2 * hB + r;                                                     \
            const unsigned short* gp = msP +                                        \
                (((((size_t)b * 66 + y) * 32) + ((sv) * 4 + c4)) * 66 + x) * 8;     \
            unsigned short* lp = &Bs[bufv][q0 * 8];                                 \
            __builtin_amdgcn_global_load_lds(                                       \
                (const __attribute__((address_space(1))) void*)gp,                  \
                (__attribute__((address_space(3))) void*)lp, 16, 0, 0);             \
        }                                                                           \
    }                                                                               \
} while (0)

    STAGE(0, 0);
    __syncthreads();

    for (int s = 0; s < 8; ++s) {
        int cur = s & 1;
        if (s < 7) STAGE(cur ^ 1, s + 1);
#pragma unroll
        for (int khw = 0; khw < 9; ++khw) {
            int kh = khw / 3, kw = khw - 3 * (khw / 3);
            bf16x8 a[4];
#pragma unroll
            for (int mf = 0; mf < 4; ++mf)
                a[mf] = Wbp[((khw * 8 + s) * 4 + c4l) * 128 + wm * 64 + mf * 16 + lrow];
            bf16x8 bf[4];
#pragma unroll
            for (int nf = 0; nf < 4; ++nf) {
                int chunk = ((wn + kh) * 4 + c4l) * 66 + nf * 16 + lrow + kw;
                bf[nf] = *(const bf16x8*)&Bs[cur][chunk * 8];
            }
#pragma unroll
            for (int mf = 0; mf < 4; ++mf)
#pragma unroll
                for (int nf = 0; nf < 4; ++nf)
                    acc[mf][nf] = __builtin_amdgcn_mfma_f32_16x16x32_bf16(
                        a[mf], bf[nf], acc[mf][nf], 0, 0, 0);
        }
        __syncthreads();
    }

    // epilogue: D layout col=lane&15 (pixel), row=(lane>>4)*4+j (co)
    int h = 2 * hB + wn;
#pragma unroll
    for (int mf = 0; mf < 4; ++mf) {
        int co0 = wm * 64 + mf * 16 + c4l * 4;
#pragma unroll
        for (int nf = 0; nf < 4; ++nf) {
            int x = nf * 16 + lrow;
            float* dst = vals + (((size_t)b * 128 + co0) * HW) + h * 64 + x;
            f32x4 v = acc[mf][nf];
#pragma unroll
            for (int j = 0; j < 4; ++j)
                dst[(size_t)j * HW] = v[j] + biasS[co0 + j];
        }
    }
#undef STAGE
}

// ---------------- K1: per-pixel qt, qb, logit_main ----------------
__global__ __launch_bounds__(256) void k1(
    const float* __restrict__ ms,
    const float* __restrict__ WfT, const float* __restrict__ WkT,
    const float* __restrict__ WqtT,
    const float* __restrict__ Wf_b, const float* __restrict__ Wk_b,
    const float* __restrict__ bqt, const float* __restrict__ wqb,
    const float* __restrict__ bqb,
    float* __restrict__ qt, float* __restrict__ qb, float* __restrict__ lm) {
    __shared__ float Xs[256][16];
    __shared__ float qm[256][16];   // rows 0..127 = q, 128..255 = mkey
    int t = threadIdx.x;
    int blk = blockIdx.x;           // 2048 blocks
    int b = blk >> 8;
    int hw0 = (blk & 255) << 4;
    const float* msb = ms + (size_t)b * (CF * HW) + hw0;
    for (int l = t; l < 4096; l += 256) {
        int f = l >> 4, px = l & 15;
        Xs[f][px] = msb[f * HW + px];
    }
    __syncthreads();
    {
        int row = t & 127;
        const float* WT = (t < 128) ? WfT : WkT;
        float acc[16];
#pragma unroll
        for (int px = 0; px < 16; ++px) acc[px] = 0.f;
        for (int f = 0; f < 256; ++f) {
            float wv = WT[f * 128 + row];
            const float4* xr = (const float4*)&Xs[f][0];
            float4 a0 = xr[0], a1 = xr[1], a2 = xr[2], a3 = xr[3];
            acc[0] += wv * a0.x; acc[1] += wv * a0.y; acc[2] += wv * a0.z; acc[3] += wv * a0.w;
            acc[4] += wv * a1.x; acc[5] += wv * a1.y; acc[6] += wv * a1.z; acc[7] += wv * a1.w;
            acc[8] += wv * a2.x; acc[9] += wv * a2.y; acc[10] += wv * a2.z; acc[11] += wv * a2.w;
            acc[12] += wv * a3.x; acc[13] += wv * a3.y; acc[14] += wv * a3.z; acc[15] += wv * a3.w;
        }
        float bias = (t < 128) ? Wf_b[row] : Wk_b[row];
#pragma unroll
        for (int px = 0; px < 16; ++px) qm[t][px] = acc[px] + bias;
    }
    __syncthreads();
    if (t < 128) {
        int c = t;
        float acc[16];
#pragma unroll
        for (int px = 0; px < 16; ++px) acc[px] = 0.f;
        for (int f = 0; f < 256; ++f) {
            float wv = WqtT[f * 128 + c];
            const float4* xr = (const float4*)&Xs[f][0];
            float4 a0 = xr[0], a1 = xr[1], a2 = xr[2], a3 = xr[3];
            acc[0] += wv * a0.x; acc[1] += wv * a0.y; acc[2] += wv * a0.z; acc[3] += wv * a0.w;
            acc[4] += wv * a1.x; acc[5] += wv * a1.y; acc[6] += wv * a1.z; acc[7] += wv * a1.w;
            acc[8] += wv * a2.x; acc[9] += wv * a2.y; acc[10] += wv * a2.z; acc[11] += wv * a2.w;
            acc[12] += wv * a3.x; acc[13] += wv * a3.y; acc[14] += wv * a3.z; acc[15] += wv * a3.w;
        }
        float bb = bqt[c];
        float* dst = qt + (size_t)b * (CC * HW) + c * HW + hw0;
#pragma unroll
        for (int px = 0; px < 16; ++px) dst[px] = acc[px] + bb;
    } else if (t < 144) {
        int px = t - 128;
        float s = 0.f;
        for (int c = 0; c < 128; ++c) s += qm[c][px] * qm[c + 128][px];
        lm[b * HW + hw0 + px] = s;
    } else if (t < 160) {
        int px = t - 144;
        float s = *bqb;
        for (int f = 0; f < 256; ++f) s += wqb[f] * Xs[f][px];
        qb[b * HW + hw0 + px] = s;
    }
}

// ---------------- K3: fused logits -> softmax -> combine ----------------
__global__ __launch_bounds__(256) void k3(
    const float* __restrict__ ctx, const float* __restrict__ qt,
    const float* __restrict__ vals, const float* __restrict__ qb,
    const float* __restrict__ lm, float* __restrict__ out) {
    __shared__ float qtS[128][16];
    __shared__ float vS[128][16];
    __shared__ float ctxS[128][64];    // [c][i*32+s]
    __shared__ float part[64][4];
    __shared__ float logitsS[3][64];
    __shared__ float attnS[4][64];
    __shared__ float qbS[16], lmS[16];
    int t = threadIdx.x;
    int blk = blockIdx.x;              // 2048 = 8*64*4
    int b = blk >> 8;
    int h = (blk >> 2) & 63;
    int q0 = blk & 3;
    int p0 = q0 * 16;
    int x0 = q0 * 32;
    for (int l = t; l < 2048; l += 256) {
        int c = l >> 4, p = l & 15;
        size_t off = (size_t)b * (CC * HW) + c * HW + h * 64 + p0 + p;
        qtS[c][p] = qt[off];
        vS[c][p]  = vals[off];
    }
    if (t < 16) {
        qbS[t] = qb[b * HW + h * 64 + p0 + t];
        lmS[t] = lm[b * HW + h * 64 + p0 + t];
    }
    for (int n = 0; n < 3; ++n) {
        __syncthreads();
        const float* cb = ctx + (size_t)(n * B + b) * CC * YX;
        for (int l = t; l < 8192; l += 256) {
            int c = l >> 6, r = l & 63;
            ctxS[c][r] = cb[(size_t)c * YX + (2 * h + (r >> 5)) * 128 + x0 + (r & 31)];
        }
        __syncthreads();
        {
            int d = t >> 2, qq = t & 3;
            int s = d & 31;
            int p = s >> 1;
            float sum = 0.f;
            int cbase = qq * 32;
            for (int c = 0; c < 32; ++c)
                sum += ctxS[cbase + c][d] * qtS[cbase + c][p];
            part[d][qq] = sum;
        }
        __syncthreads();
        if (t < 64)
            logitsS[n][t] = part[t][0] + part[t][1] + part[t][2] + part[t][3]
                            + qbS[(t & 31) >> 1];
    }
    __syncthreads();
    if (t < 64) {
        int p = (t & 31) >> 1;
        float l0 = logitsS[0][t], l1 = logitsS[1][t], l2 = logitsS[2][t], l3 = lmS[p];
        float m = fmaxf(fmaxf(l0, l1), fmaxf(l2, l3));
        float e0 = __expf(l0 - m), e1 = __expf(l1 - m), e2 = __expf(l2 - m), e3 = __expf(l3 - m);
        float inv = 1.f / (e0 + e1 + e2 + e3);
        attnS[0][t] = e0 * inv; attnS[1][t] = e1 * inv;
        attnS[2][t] = e2 * inv; attnS[3][t] = e3 * inv;
    }
    __syncthreads();
    int sp = t & 63;
    int i = sp >> 5, s = sp & 31, p = s >> 1;
    int ch = t >> 6;
    float acc[32];
    float am = attnS[3][sp];
#pragma unroll
    for (int cc = 0; cc < 32; ++cc) acc[cc] = am * vS[ch * 32 + cc][p];
    for (int n = 0; n < 3; ++n) {
        __syncthreads();
        const float* cb = ctx + (size_t)(n * B + b) * CC * YX;
        for (int l = t; l < 8192; l += 256) {
            int c = l >> 6, r = l & 63;
            ctxS[c][r] = cb[(size_t)c * YX + (2 * h + (r >> 5)) * 128 + x0 + (r & 31)];
        }
        __syncthreads();
        float an = attnS[n][sp];
#pragma unroll
        for (int cc = 0; cc < 32; ++cc) acc[cc] += an * ctxS[ch * 32 + cc][sp];
    }
#pragma unroll
    for (int cc = 0; cc < 32; ++cc) {
        int c = ch * 32 + cc;
        out[((size_t)b * CC + c) * YX + (2 * h + i) * 128 + x0 + s] = acc[cc];
    }
}

extern "C" void kernel_launch(void* const* d_in, const int* in_sizes, int n_in,
                              void* d_out, int out_size, void* d_ws, size_t ws_size,
                              hipStream_t stream) {
    const float* ctx  = (const float*)d_in[0];
    const float* ms   = (const float*)d_in[1];
    const float* Wc_w = (const float*)d_in[2];
    const float* Wc_b = (const float*)d_in[3];
    const float* Wf_w = (const float*)d_in[4];
    const float* Wf_b = (const float*)d_in[5];
    const float* Wk_w = (const float*)d_in[6];
    const float* Wk_b = (const float*)d_in[7];
    const float* Wv_w = (const float*)d_in[8];
    const float* Wv_b = (const float*)d_in[9];
    float* out = (float*)d_out;
    float* ws = (float*)d_ws;
    float* qt   = ws + WS_QT;
    float* vals = ws + WS_VALS;
    float* qb   = ws + WS_QB;
    float* lmp  = ws + WS_LM;
    float* WfT  = ws + WS_WFT;
    float* WkT  = ws + WS_WKT;
    float* WqtT = ws + WS_WQTT;
    float* bqt  = ws + WS_BQT;
    float* wqb  = ws + WS_WQB;
    float* bqb  = ws + WS_BQB;
    unsigned short* msPp = (unsigned short*)(ws + WS_MSP);
    unsigned short* Wbp  = (unsigned short*)(ws + WS_WB);

    hipMemsetAsync(msPp, 0, (size_t)MSP_USHORTS * 2, stream);
    hipLaunchKernelGGL(k0a, dim3(128), dim3(256), 0, stream, Wf_w, Wk_w, WfT, WkT);
    hipLaunchKernelGGL(k0b, dim3(130), dim3(256), 0, stream, Wc_w, Wc_b, Wf_w, Wf_b,
                       WqtT, bqt, wqb, bqb);
    hipLaunchKernelGGL(k0c, dim3(1152), dim3(256), 0, stream, Wv_w, Wbp);
    hipLaunchKernelGGL(k2p, dim3(4096), dim3(256), 0, stream, ms, msPp);
    hipLaunchKernelGGL(k1, dim3(2048), dim3(256), 0, stream, ms, WfT, WkT, WqtT,
                       Wf_b, Wk_b, bqt, wqb, bqb, qt, qb, lmp);
    hipLaunchKernelGGL(k2m, dim3(256), dim3(256), 0, stream, msPp, Wbp, Wv_b, vals);
    hipLaunchKernelGGL(k3, dim3(2048), dim3(256), 0, stream, ctx, qt, vals, qb, lmp, out);
}

// Round 3
// 197.906 us; speedup vs baseline: 3.1045x; 1.5241x over previous
//
#include <hip/hip_runtime.h>

#define NCTX 3
#define B 8
#define CC 128
#define CF 256
#define H 64
#define W 64
#define HW 4096
#define YX 16384   // (2H)*(2W)

// workspace layout (float offsets)
#define WS_QT    0          // B*CC*HW = 4194304
#define WS_VALS  4194304    // B*CC*HW
#define WS_BIAS  8388608    // bias448 (448 floats, slot 32768)
#define WS_LM    8421376    // B*HW
#define WS_WALL  8454144    // bf16 Wall: 8*4*448*8 = 114688 ushorts = 57344 floats (2 slots)
#define WS_WQTT  8519680    // CF*CC  [f][c]
#define WS_BQT   8552448    // CC
#define WS_WQB   8552576    // CF
#define WS_BQB   8552832    // 1  (pad to 8552960)
#define WS_MSP   8552960    // bf16 msP: 8*66*32*66*8 = 8921088 ushorts = 4460544 floats
#define WS_WB    13013504   // bf16 Wb: 9*8*4*128*8 = 294912 ushorts = 147456 floats
#define MSP_USHORTS 8921088

typedef __attribute__((ext_vector_type(8))) short bf16x8;
typedef __attribute__((ext_vector_type(4))) float f32x4;
typedef __attribute__((ext_vector_type(8))) unsigned short u16x8;

__device__ __forceinline__ unsigned short f2b(float f) {
    union { float f; unsigned u; } c; c.f = f;
    unsigned u = c.u + 0x7FFFu + ((c.u >> 16) & 1u);
    return (unsigned short)(u >> 16);
}

// ---------------- K0b: fused attention-key weights ----------------
__global__ void k0b(const float* __restrict__ Wc_w, const float* __restrict__ Wc_b,
                    const float* __restrict__ Wf_w, const float* __restrict__ Wf_b,
                    float* __restrict__ WqtT, float* __restrict__ bqt,
                    float* __restrict__ wqb, float* __restrict__ bqb) {
    int i = blockIdx.x * 256 + threadIdx.x;
    if (i < 32768) {
        int f = i >> 7, c = i & 127;        // layout [f][c]
        float s = 0.f;
        for (int o = 0; o < 128; ++o) s += Wc_w[o * 128 + c] * Wf_w[o * 256 + f];
        WqtT[i] = s;
    } else if (i < 32896) {
        int c = i - 32768;
        float s = 0.f;
        for (int o = 0; o < 128; ++o) s += Wc_w[o * 128 + c] * Wf_b[o];
        bqt[c] = s;
    } else if (i < 33152) {
        int f = i - 32896;
        float s = 0.f;
        for (int o = 0; o < 128; ++o) s += Wc_b[o] * Wf_w[o * 256 + f];
        wqb[f] = s;
    } else if (i == 33152) {
        float s = 0.f;
        for (int o = 0; o < 128; ++o) s += Wc_b[o] * Wf_b[o];
        *bqb = s;
    }
}

// ---------------- K0c: conv weights -> bf16 Wb[khw][s][c4][co][8ci] ----------------
__global__ void k0c(const float* __restrict__ Wv, unsigned short* __restrict__ Wb) {
    int o = blockIdx.x * 256 + threadIdx.x;   // 294912 threads exactly
    int ci8 = o & 7;
    int co  = (o >> 3) & 127;
    int c4  = (o >> 10) & 3;
    int s   = (o >> 12) & 7;
    int khw = o >> 15;                        // [0,9)
    int ci  = s * 32 + c4 * 8 + ci8;
    int kh  = khw / 3, kw = khw - kh * 3;
    Wb[o] = f2b(Wv[((co * 256 + ci) * 3 + kh) * 3 + kw]);
}

// ---------------- K0d: pack Wall[s][c4][row448][8ci] + bias448 ----------------
// rows: 0..127 qt(c=row); 128+2p=q[p], 129+2p=mkey[p]; 384=(wqb,bqb); 385=(0,-1); rest 0
__global__ void k0d(const float* __restrict__ WqtT, const float* __restrict__ bqt,
                    const float* __restrict__ Wf_w, const float* __restrict__ Wf_b,
                    const float* __restrict__ Wk_w, const float* __restrict__ Wk_b,
                    const float* __restrict__ wqb, const float* __restrict__ bqb,
                    unsigned short* __restrict__ Wall, float* __restrict__ bias448) {
    int o = blockIdx.x * 256 + threadIdx.x;   // 114688 threads = 448 blocks
    int ci8 = o & 7;
    int idx = o >> 3;                         // sc4*448 + row
    int row = idx % 448;
    int sc4 = idx / 448;                      // s*4 + c4
    int f = (sc4 >> 2) * 32 + (sc4 & 3) * 8 + ci8;
    float w;
    if (row < 128)       w = WqtT[f * 128 + row];
    else if (row < 384)  { int p = (row - 128) >> 1;
                           w = (row & 1) ? Wk_w[p * 256 + f] : Wf_w[p * 256 + f]; }
    else if (row == 384) w = wqb[f];
    else                 w = 0.f;
    Wall[o] = f2b(w);
    if (o < 448) {
        float bb;
        if (o < 128)       bb = bqt[o];
        else if (o < 384)  { int p = (o - 128) >> 1;
                             bb = (o & 1) ? Wk_b[p] : Wf_b[p]; }
        else if (o == 384) bb = *bqb;
        else if (o == 385) bb = -1.f;
        else               bb = 0.f;
        bias448[o] = bb;
    }
}

// ---------------- K2p: ms -> padded, transposed bf16 msP[b][y66][g32][x66][8ci] ----
__global__ __launch_bounds__(256) void k2p(const float* __restrict__ ms,
                                           unsigned short* __restrict__ msP) {
    __shared__ float Ls[32][65];
    int t = threadIdx.x;
    int blk = blockIdx.x;          // 4096 = 8b * 64h * 8s
    int s = blk & 7;
    int h = (blk >> 3) & 63;
    int b = blk >> 9;
    const float* src = ms + ((size_t)b * 256 + s * 32) * HW + h * 64;
    for (int l = t; l < 2048; l += 256) {
        int ci = l >> 6, w = l & 63;
        Ls[ci][w] = src[ci * HW + w];
    }
    __syncthreads();
    int w = t & 63, gi = t >> 6;   // gi in [0,4)
    u16x8 v;
#pragma unroll
    for (int j = 0; j < 8; ++j) v[j] = f2b(Ls[gi * 8 + j][w]);
    size_t off = ((((size_t)b * 66 + (h + 1)) * 32) + (s * 4 + gi)) * 66 + (w + 1);
    *(u16x8*)&msP[off * 8] = v;
}

// ---------------- K1m: fused qt/q/mkey/lm via MFMA implicit GEMM ----------------
// grid 256 = 8b*32hB; block 512 = 8 waves: wm in [0,4) (112-row chunk), wn in [0,2) (image row)
__global__ __launch_bounds__(512, 1) void k1m(const unsigned short* __restrict__ msP,
                                              const unsigned short* __restrict__ Wall,
                                              const float* __restrict__ bias448,
                                              float* __restrict__ qt, float* __restrict__ lm) {
    __shared__ unsigned short Bs[2][2][4][64][8];  // [buf][r][c4][x][ci8] = 8 KB each
    __shared__ float biasS[448];
    __shared__ float lmAcc[2][64];
    int t = threadIdx.x;
    int lane = t & 63, wid = t >> 6;
    int wm = wid >> 1, wn = wid & 1;
    int b = blockIdx.x >> 5, hB = blockIdx.x & 31;
    int c4l = lane >> 4, lrow = lane & 15;
    for (int i = t; i < 448; i += 512) biasS[i] = bias448[i];
    if (t < 128) lmAcc[t >> 6][t & 63] = 0.f;

    f32x4 acc[7][4];
#pragma unroll
    for (int mf = 0; mf < 7; ++mf)
#pragma unroll
        for (int nf = 0; nf < 4; ++nf) acc[mf][nf] = (f32x4){0.f, 0.f, 0.f, 0.f};

    const bf16x8* Wallp = (const bf16x8*)Wall;

#define STAGE1(bufv, sv) do {                                                       \
    int r_ = wid >> 2, c4_ = wid & 3;                                               \
    const unsigned short* gp = msP +                                                \
        (((((size_t)b * 66 + (2 * hB + r_ + 1)) * 32) + ((sv) * 4 + c4_)) * 66      \
         + (lane + 1)) * 8;                                                         \
    unsigned short* lp = &Bs[bufv][r_][c4_][0][0];                                  \
    __builtin_amdgcn_global_load_lds(                                               \
        (const __attribute__((address_space(1))) void*)gp,                          \
        (__attribute__((address_space(3))) void*)lp, 16, 0, 0);                     \
} while (0)

    STAGE1(0, 0);
    __syncthreads();

    for (int s = 0; s < 8; ++s) {
        int cur = s & 1;
        if (s < 7) STAGE1(cur ^ 1, s + 1);
        bf16x8 bf[4];
#pragma unroll
        for (int nf = 0; nf < 4; ++nf)
            bf[nf] = *(const bf16x8*)&Bs[cur][wn][c4l][nf * 16 + lrow][0];
#pragma unroll
        for (int mf = 0; mf < 7; ++mf) {
            bf16x8 a = Wallp[(size_t)(s * 4 + c4l) * 448 + wm * 112 + mf * 16 + lrow];
#pragma unroll
            for (int nf = 0; nf < 4; ++nf)
                acc[mf][nf] = __builtin_amdgcn_mfma_f32_16x16x32_bf16(
                    a, bf[nf], acc[mf][nf], 0, 0, 0);
        }
        __syncthreads();
    }

    // epilogue: D layout col=lane&15 (px), row=(lane>>4)*4+j
    int h = 2 * hB + wn;
    float lmp[4] = {0.f, 0.f, 0.f, 0.f};
#pragma unroll
    for (int mf = 0; mf < 7; ++mf) {
        int base = wm * 112 + mf * 16;
        int r0 = base + c4l * 4;
        if (base < 128) {
#pragma unroll
            for (int nf = 0; nf < 4; ++nf) {
                int x = nf * 16 + lrow;
                float* dst = qt + ((size_t)b * 128 + r0) * HW + h * 64 + x;
                f32x4 v = acc[mf][nf];
#pragma unroll
                for (int j = 0; j < 4; ++j)
                    dst[(size_t)j * HW] = v[j] + biasS[r0 + j];
            }
        } else {
            float b0 = biasS[r0], b1 = biasS[r0 + 1], b2 = biasS[r0 + 2], b3 = biasS[r0 + 3];
#pragma unroll
            for (int nf = 0; nf < 4; ++nf) {
                f32x4 v = acc[mf][nf];
                lmp[nf] += (v[0] + b0) * (v[1] + b1) + (v[2] + b2) * (v[3] + b3);
            }
        }
    }
    if (wm != 0) {
#pragma unroll
        for (int nf = 0; nf < 4; ++nf) {
            lmp[nf] += __shfl_xor(lmp[nf], 16);
            lmp[nf] += __shfl_xor(lmp[nf], 32);
        }
        if (c4l == 0) {
#pragma unroll
            for (int nf = 0; nf < 4; ++nf)
                atomicAdd(&lmAcc[wn][nf * 16 + lrow], lmp[nf]);
        }
    }
    __syncthreads();
    if (t < 128) {
        int wn2 = t >> 6, px = t & 63;
        lm[b * HW + (2 * hB + wn2) * 64 + px] = lmAcc[wn2][px];
    }
#undef STAGE1
}

// ---------------- K2m: implicit-GEMM MFMA 3x3 conv ----------------
__global__ __launch_bounds__(256, 1) void k2m(const unsigned short* __restrict__ msP,
                                              const unsigned short* __restrict__ Wb,
                                              const float* __restrict__ Wv_b,
                                              float* __restrict__ vals) {
    __shared__ unsigned short Bs[2][8448];   // [buf][(r*4+c4)*66 + x][8ci]
    __shared__ float biasS[128];
    int t = threadIdx.x;
    int lane = t & 63, wid = t >> 6;
    int wm = wid >> 1, wn = wid & 1;
    int b = blockIdx.x >> 5, hB = blockIdx.x & 31;
    int c4l = lane >> 4, lrow = lane & 15;
    if (t < 128) biasS[t] = Wv_b[t];

    f32x4 acc[4][4];
#pragma unroll
    for (int mf = 0; mf < 4; ++mf)
#pragma unroll
        for (int nf = 0; nf < 4; ++nf) acc[mf][nf] = (f32x4){0.f, 0.f, 0.f, 0.f};

    const bf16x8* Wbp = (const bf16x8*)Wb;

#define STAGE(bufv, sv) do {                                                        \
    for (int iter = 0; iter < 5; ++iter) {                                          \
        int q0 = iter * 256 + (wid << 6);                                           \
        int q = q0 + lane;                                                          \
        if (q < 1056) {                                                             \
            int r = q / 264; int rem = q - r * 264;                                 \
            int c4 = rem / 66; int x = rem - c4 * 66;                               \
            int y = 2 * hB + r;                                                     \
            const unsigned short* gp = msP +                                        \
                (((((size_t)b * 66 + y) * 32) + ((sv) * 4 + c4)) * 66 + x) * 8;     \
            unsigned short* lp = &Bs[bufv][q0 * 8];                                 \
            __builtin_amdgcn_global_load_lds(                                       \
                (const __attribute__((address_space(1))) void*)gp,                  \
                (__attribute__((address_space(3))) void*)lp, 16, 0, 0);             \
        }                                                                           \
    }                                                                               \
} while (0)

    STAGE(0, 0);
    __syncthreads();

    for (int s = 0; s < 8; ++s) {
        int cur = s & 1;
        if (s < 7) STAGE(cur ^ 1, s + 1);
#pragma unroll
        for (int khw = 0; khw < 9; ++khw) {
            int kh = khw / 3, kw = khw - 3 * (khw / 3);
            bf16x8 a[4];
#pragma unroll
            for (int mf = 0; mf < 4; ++mf)
                a[mf] = Wbp[((khw * 8 + s) * 4 + c4l) * 128 + wm * 64 + mf * 16 + lrow];
            bf16x8 bf[4];
#pragma unroll
            for (int nf = 0; nf < 4; ++nf) {
                int chunk = ((wn + kh) * 4 + c4l) * 66 + nf * 16 + lrow + kw;
                bf[nf] = *(const bf16x8*)&Bs[cur][chunk * 8];
            }
#pragma unroll
            for (int mf = 0; mf < 4; ++mf)
#pragma unroll
                for (int nf = 0; nf < 4; ++nf)
                    acc[mf][nf] = __builtin_amdgcn_mfma_f32_16x16x32_bf16(
                        a[mf], bf[nf], acc[mf][nf], 0, 0, 0);
        }
        __syncthreads();
    }

    int h = 2 * hB + wn;
#pragma unroll
    for (int mf = 0; mf < 4; ++mf) {
        int co0 = wm * 64 + mf * 16 + c4l * 4;
#pragma unroll
        for (int nf = 0; nf < 4; ++nf) {
            int x = nf * 16 + lrow;
            float* dst = vals + (((size_t)b * 128 + co0) * HW) + h * 64 + x;
            f32x4 v = acc[mf][nf];
#pragma unroll
            for (int j = 0; j < 4; ++j)
                dst[(size_t)j * HW] = v[j] + biasS[co0 + j];
        }
    }
#undef STAGE
}

// ---------------- K3: fused logits -> softmax -> combine ----------------
__global__ __launch_bounds__(256) void k3(
    const float* __restrict__ ctx, const float* __restrict__ qt,
    const float* __restrict__ vals,
    const float* __restrict__ lm, float* __restrict__ out) {
    __shared__ float qtS[128][16];
    __shared__ float vS[128][16];
    __shared__ float ctxS[128][64];    // [c][i*32+s]
    __shared__ float part[64][4];
    __shared__ float logitsS[3][64];
    __shared__ float attnS[4][64];
    __shared__ float lmS[16];
    int t = threadIdx.x;
    int blk = blockIdx.x;              // 2048 = 8*64*4
    int b = blk >> 8;
    int h = (blk >> 2) & 63;
    int q0 = blk & 3;
    int p0 = q0 * 16;
    int x0 = q0 * 32;
    for (int l = t; l < 2048; l += 256) {
        int c = l >> 4, p = l & 15;
        size_t off = (size_t)b * (CC * HW) + c * HW + h * 64 + p0 + p;
        qtS[c][p] = qt[off];
        vS[c][p]  = vals[off];
    }
    if (t < 16) {
        lmS[t] = lm[b * HW + h * 64 + p0 + t];
    }
    for (int n = 0; n < 3; ++n) {
        __syncthreads();
        const float* cb = ctx + (size_t)(n * B + b) * CC * YX;
        for (int l = t; l < 8192; l += 256) {
            int c = l >> 6, r = l & 63;
            ctxS[c][r] = cb[(size_t)c * YX + (2 * h + (r >> 5)) * 128 + x0 + (r & 31)];
        }
        __syncthreads();
        {
            int d = t >> 2, qq = t & 3;
            int s = d & 31;
            int p = s >> 1;
            float sum = 0.f;
            int cbase = qq * 32;
            for (int c = 0; c < 32; ++c)
                sum += ctxS[cbase + c][d] * qtS[cbase + c][p];
            part[d][qq] = sum;
        }
        __syncthreads();
        if (t < 64)
            logitsS[n][t] = part[t][0] + part[t][1] + part[t][2] + part[t][3];
    }
    __syncthreads();
    if (t < 64) {
        int p = (t & 31) >> 1;
        float l0 = logitsS[0][t], l1 = logitsS[1][t], l2 = logitsS[2][t], l3 = lmS[p];
        float m = fmaxf(fmaxf(l0, l1), fmaxf(l2, l3));
        float e0 = __expf(l0 - m), e1 = __expf(l1 - m), e2 = __expf(l2 - m), e3 = __expf(l3 - m);
        float inv = 1.f / (e0 + e1 + e2 + e3);
        attnS[0][t] = e0 * inv; attnS[1][t] = e1 * inv;
        attnS[2][t] = e2 * inv; attnS[3][t] = e3 * inv;
    }
    __syncthreads();
    int sp = t & 63;
    int i = sp >> 5, s = sp & 31, p = s >> 1;
    int ch = t >> 6;
    float acc[32];
    float am = attnS[3][sp];
#pragma unroll
    for (int cc = 0; cc < 32; ++cc) acc[cc] = am * vS[ch * 32 + cc][p];
    for (int n = 0; n < 3; ++n) {
        __syncthreads();
        const float* cb = ctx + (size_t)(n * B + b) * CC * YX;
        for (int l = t; l < 8192; l += 256) {
            int c = l >> 6, r = l & 63;
            ctxS[c][r] = cb[(size_t)c * YX + (2 * h + (r >> 5)) * 128 + x0 + (r & 31)];
        }
        __syncthreads();
        float an = attnS[n][sp];
#pragma unroll
        for (int cc = 0; cc < 32; ++cc) acc[cc] += an * ctxS[ch * 32 + cc][sp];
    }
#pragma unroll
    for (int cc = 0; cc < 32; ++cc) {
        int c = ch * 32 + cc;
        out[((size_t)b * CC + c) * YX + (2 * h + i) * 128 + x0 + s] = acc[cc];
    }
}

extern "C" void kernel_launch(void* const* d_in, const int* in_sizes, int n_in,
                              void* d_out, int out_size, void* d_ws, size_t ws_size,
                              hipStream_t stream) {
    const float* ctx  = (const float*)d_in[0];
    const float* ms   = (const float*)d_in[1];
    const float* Wc_w = (const float*)d_in[2];
    const float* Wc_b = (const float*)d_in[3];
    const float* Wf_w = (const float*)d_in[4];
    const float* Wf_b = (const float*)d_in[5];
    const float* Wk_w = (const float*)d_in[6];
    const float* Wk_b = (const float*)d_in[7];
    const float* Wv_w = (const float*)d_in[8];
    const float* Wv_b = (const float*)d_in[9];
    float* out = (float*)d_out;
    float* ws = (float*)d_ws;
    float* qt     = ws + WS_QT;
    float* vals   = ws + WS_VALS;
    float* bias448= ws + WS_BIAS;
    float* lmp    = ws + WS_LM;
    float* WqtT   = ws + WS_WQTT;
    float* bqt    = ws + WS_BQT;
    float* wqb    = ws + WS_WQB;
    float* bqb    = ws + WS_BQB;
    unsigned short* Wallp = (unsigned short*)(ws + WS_WALL);
    unsigned short* msPp  = (unsigned short*)(ws + WS_MSP);
    unsigned short* Wbp   = (unsigned short*)(ws + WS_WB);

    hipMemsetAsync(msPp, 0, (size_t)MSP_USHORTS * 2, stream);
    hipLaunchKernelGGL(k0b, dim3(130), dim3(256), 0, stream, Wc_w, Wc_b, Wf_w, Wf_b,
                       WqtT, bqt, wqb, bqb);
    hipLaunchKernelGGL(k0c, dim3(1152), dim3(256), 0, stream, Wv_w, Wbp);
    hipLaunchKernelGGL(k0d, dim3(448), dim3(256), 0, stream, WqtT, bqt, Wf_w, Wf_b,
                       Wk_w, Wk_b, wqb, bqb, Wallp, bias448);
    hipLaunchKernelGGL(k2p, dim3(4096), dim3(256), 0, stream, ms, msPp);
    hipLaunchKernelGGL(k1m, dim3(256), dim3(512), 0, stream, msPp, Wallp, bias448, qt, lmp);
    hipLaunchKernelGGL(k2m, dim3(256), dim3(256), 0, stream, msPp, Wbp, Wv_b, vals);
    hipLaunchKernelGGL(k3, dim3(2048), dim3(256), 0, stream, ctx, qt, vals, lmp, out);
}

// Round 4
// 174.335 us; speedup vs baseline: 3.5242x; 1.1352x over previous
//
#include <hip/hip_runtime.h>

#define NCTX 3
#define B 8
#define CC 128
#define CF 256
#define H 64
#define W 64
#define HW 4096
#define YX 16384   // (2H)*(2W)

// workspace layout (float offsets)
#define WS_QT    0          // B*CC*HW = 4194304
#define WS_VALS  4194304    // B*CC*HW floats; ALSO aliased as msLo (8388608 ushorts) before k2m
#define WS_BIAS  8388608    // bias448 (448 floats); Wallo ushorts at +1024
#define WS_LM    8421376    // B*HW
#define WS_WALL  8454144    // bf16 Wall hi: 8*4*448*8 = 114688 ushorts = 57344 floats
#define WS_WQTT  8519680    // CF*CC  [f][c]
#define WS_BQT   8552448    // CC
#define WS_WQB   8552576    // CF
#define WS_BQB   8552832    // 1  (pad to 8552960)
#define WS_MSP   8552960    // bf16 msP hi: 8*66*32*66*8 = 8921088 ushorts
#define WS_WB    13013504   // bf16 Wb: 9*8*4*128*8 = 294912 ushorts = 147456 floats

typedef __attribute__((ext_vector_type(8))) short bf16x8;
typedef __attribute__((ext_vector_type(4))) float f32x4;
typedef __attribute__((ext_vector_type(8))) unsigned short u16x8;

__device__ __forceinline__ unsigned short f2b(float f) {
    union { float f; unsigned u; } c; c.f = f;
    unsigned u = c.u + 0x7FFFu + ((c.u >> 16) & 1u);
    return (unsigned short)(u >> 16);
}
__device__ __forceinline__ float b2f(unsigned short u) {
    union { unsigned u; float f; } c; c.u = ((unsigned)u) << 16;
    return c.f;
}

// ---------------- K0b: fused attention-key weights (fp32) ----------------
__global__ void k0b(const float* __restrict__ Wc_w, const float* __restrict__ Wc_b,
                    const float* __restrict__ Wf_w, const float* __restrict__ Wf_b,
                    float* __restrict__ WqtT, float* __restrict__ bqt,
                    float* __restrict__ wqb, float* __restrict__ bqb) {
    int i = blockIdx.x * 256 + threadIdx.x;
    if (i < 32768) {
        int f = i >> 7, c = i & 127;        // layout [f][c]
        float s = 0.f;
        for (int o = 0; o < 128; ++o) s += Wc_w[o * 128 + c] * Wf_w[o * 256 + f];
        WqtT[i] = s;
    } else if (i < 32896) {
        int c = i - 32768;
        float s = 0.f;
        for (int o = 0; o < 128; ++o) s += Wc_w[o * 128 + c] * Wf_b[o];
        bqt[c] = s;
    } else if (i < 33152) {
        int f = i - 32896;
        float s = 0.f;
        for (int o = 0; o < 128; ++o) s += Wc_b[o] * Wf_w[o * 256 + f];
        wqb[f] = s;
    } else if (i == 33152) {
        float s = 0.f;
        for (int o = 0; o < 128; ++o) s += Wc_b[o] * Wf_b[o];
        *bqb = s;
    }
}

// ---------------- K0c: conv weights -> bf16 Wb[khw][s][c4][co][8ci] ----------------
__global__ void k0c(const float* __restrict__ Wv, unsigned short* __restrict__ Wb) {
    int o = blockIdx.x * 256 + threadIdx.x;   // 294912 threads exactly
    int ci8 = o & 7;
    int co  = (o >> 3) & 127;
    int c4  = (o >> 10) & 3;
    int s   = (o >> 12) & 7;
    int khw = o >> 15;                        // [0,9)
    int ci  = s * 32 + c4 * 8 + ci8;
    int kh  = khw / 3, kw = khw - kh * 3;
    Wb[o] = f2b(Wv[((co * 256 + ci) * 3 + kh) * 3 + kw]);
}

// ---------------- K0d: pack Wall hi/lo [s][c4][row448][8ci] + bias448 ----------------
// rows: 0..127 qt(c=row); 128+2p=q[p], 129+2p=mkey[p]; 384=(wqb,bqb); 385=(0,-1); rest 0
__global__ void k0d(const float* __restrict__ WqtT, const float* __restrict__ bqt,
                    const float* __restrict__ Wf_w, const float* __restrict__ Wf_b,
                    const float* __restrict__ Wk_w, const float* __restrict__ Wk_b,
                    const float* __restrict__ wqb, const float* __restrict__ bqb,
                    unsigned short* __restrict__ Wall, unsigned short* __restrict__ Wallo,
                    float* __restrict__ bias448) {
    int o = blockIdx.x * 256 + threadIdx.x;   // 114688 threads = 448 blocks
    int ci8 = o & 7;
    int idx = o >> 3;                         // sc4*448 + row
    int row = idx % 448;
    int sc4 = idx / 448;                      // s*4 + c4
    int f = (sc4 >> 2) * 32 + (sc4 & 3) * 8 + ci8;
    float w;
    if (row < 128)       w = WqtT[f * 128 + row];
    else if (row < 384)  { int p = (row - 128) >> 1;
                           w = (row & 1) ? Wk_w[p * 256 + f] : Wf_w[p * 256 + f]; }
    else if (row == 384) w = wqb[f];
    else                 w = 0.f;
    unsigned short hi = f2b(w);
    Wall[o] = hi;
    Wallo[o] = f2b(w - b2f(hi));
    if (o < 448) {
        float bb;
        if (o < 128)       bb = bqt[o];
        else if (o < 384)  { int p = (o - 128) >> 1;
                             bb = (o & 1) ? Wk_b[p] : Wf_b[p]; }
        else if (o == 384) bb = *bqb;
        else if (o == 385) bb = -1.f;
        else               bb = 0.f;
        bias448[o] = bb;
    }
}

// ---------------- K2z: zero ONLY the msP halo (replaces 17.8MB memset) ----------------
__global__ void k2z(unsigned short* __restrict__ msP) {
    int i = blockIdx.x * 256 + threadIdx.x;   // 66560 exactly (260 blocks)
    size_t off;
    if (i < 33792) {          // rows y=0,65: 8b*2*32g*66x
        int x = i % 66; int r = i / 66;
        int g = r & 31, rowi = (r >> 5) & 1, b = r >> 6;
        off = ((((size_t)b * 66 + rowi * 65) * 32) + g) * 66 + x;
    } else {                  // cols x=0,65 for y=1..64: 8b*64*32g*2
        int k = i - 33792;
        int xi = k & 1; int g = (k >> 1) & 31; int y1 = (k >> 6) & 63; int b = k >> 12;
        off = ((((size_t)b * 66 + (y1 + 1)) * 32) + g) * 66 + xi * 65;
    }
    *(u16x8*)&msP[off * 8] = (u16x8){0, 0, 0, 0, 0, 0, 0, 0};
}

// ---------------- K2p: ms -> padded bf16 msP (hi) + unpadded residual msLo ----------
__global__ __launch_bounds__(256) void k2p(const float* __restrict__ ms,
                                           unsigned short* __restrict__ msP,
                                           unsigned short* __restrict__ msLo) {
    __shared__ float Ls[32][65];
    int t = threadIdx.x;
    int blk = blockIdx.x;          // 4096 = 8b * 64h * 8s
    int s = blk & 7;
    int h = (blk >> 3) & 63;
    int b = blk >> 9;
    const float* src = ms + ((size_t)b * 256 + s * 32) * HW + h * 64;
    for (int l = t; l < 2048; l += 256) {
        int ci = l >> 6, w = l & 63;
        Ls[ci][w] = src[ci * HW + w];
    }
    __syncthreads();
    int w = t & 63, gi = t >> 6;   // gi in [0,4)
    u16x8 vh, vl;
#pragma unroll
    for (int j = 0; j < 8; ++j) {
        float f = Ls[gi * 8 + j][w];
        unsigned short hb = f2b(f);
        vh[j] = hb;
        vl[j] = f2b(f - b2f(hb));
    }
    size_t offH = ((((size_t)b * 66 + (h + 1)) * 32) + (s * 4 + gi)) * 66 + (w + 1);
    *(u16x8*)&msP[offH * 8] = vh;
    size_t offL = ((((size_t)b * 64 + h) * 32) + (s * 4 + gi)) * 64 + w;
    *(u16x8*)&msLo[offL * 8] = vl;
}

// ---------------- K1m: fused qt/q/mkey/lm via split-bf16 MFMA implicit GEMM ----------
// grid 256 = 8b*32hB; block 512 = 8 waves: wm in [0,4) (112-row chunk), wn in [0,2)
__global__ __launch_bounds__(512, 1) void k1m(const unsigned short* __restrict__ msP,
                                              const unsigned short* __restrict__ msLo,
                                              const unsigned short* __restrict__ Wall,
                                              const unsigned short* __restrict__ Wallo,
                                              const float* __restrict__ bias448,
                                              float* __restrict__ qt, float* __restrict__ lm) {
    __shared__ unsigned short Bs[2][2][2][4][64][8];  // [buf][plane][r][c4][x][ci8] = 32 KB
    __shared__ float biasS[448];
    __shared__ float lmAcc[2][64];
    int t = threadIdx.x;
    int lane = t & 63, wid = t >> 6;
    int wm = wid >> 1, wn = wid & 1;
    int b = blockIdx.x >> 5, hB = blockIdx.x & 31;
    int c4l = lane >> 4, lrow = lane & 15;
    for (int i = t; i < 448; i += 512) biasS[i] = bias448[i];
    if (t < 128) lmAcc[t >> 6][t & 63] = 0.f;

    f32x4 acc[7][4];
#pragma unroll
    for (int mf = 0; mf < 7; ++mf)
#pragma unroll
        for (int nf = 0; nf < 4; ++nf) acc[mf][nf] = (f32x4){0.f, 0.f, 0.f, 0.f};

    const bf16x8* Whip = (const bf16x8*)Wall;
    const bf16x8* Wlop = (const bf16x8*)Wallo;

#define STAGE1(bufv, sv) do {                                                       \
    int r_ = wid >> 2, c4_ = wid & 3;                                               \
    const unsigned short* gph = msP +                                               \
        (((((size_t)b * 66 + (2 * hB + r_ + 1)) * 32) + ((sv) * 4 + c4_)) * 66      \
         + (lane + 1)) * 8;                                                         \
    __builtin_amdgcn_global_load_lds(                                               \
        (const __attribute__((address_space(1))) void*)gph,                         \
        (__attribute__((address_space(3))) void*)&Bs[bufv][0][r_][c4_][0][0],       \
        16, 0, 0);                                                                  \
    const unsigned short* gpl = msLo +                                              \
        (((((size_t)b * 64 + (2 * hB + r_)) * 32) + ((sv) * 4 + c4_)) * 64          \
         + lane) * 8;                                                               \
    __builtin_amdgcn_global_load_lds(                                               \
        (const __attribute__((address_space(1))) void*)gpl,                         \
        (__attribute__((address_space(3))) void*)&Bs[bufv][1][r_][c4_][0][0],       \
        16, 0, 0);                                                                  \
} while (0)

    STAGE1(0, 0);
    __syncthreads();

    for (int s = 0; s < 8; ++s) {
        int cur = s & 1;
        if (s < 7) STAGE1(cur ^ 1, s + 1);
        bf16x8 bh[4], bl[4];
#pragma unroll
        for (int nf = 0; nf < 4; ++nf) {
            bh[nf] = *(const bf16x8*)&Bs[cur][0][wn][c4l][nf * 16 + lrow][0];
            bl[nf] = *(const bf16x8*)&Bs[cur][1][wn][c4l][nf * 16 + lrow][0];
        }
#pragma unroll
        for (int mf = 0; mf < 7; ++mf) {
            size_t widx = (size_t)(s * 4 + c4l) * 448 + wm * 112 + mf * 16 + lrow;
            bf16x8 ah = Whip[widx];
            bf16x8 al = Wlop[widx];
#pragma unroll
            for (int nf = 0; nf < 4; ++nf) {
                acc[mf][nf] = __builtin_amdgcn_mfma_f32_16x16x32_bf16(ah, bh[nf], acc[mf][nf], 0, 0, 0);
                acc[mf][nf] = __builtin_amdgcn_mfma_f32_16x16x32_bf16(ah, bl[nf], acc[mf][nf], 0, 0, 0);
                acc[mf][nf] = __builtin_amdgcn_mfma_f32_16x16x32_bf16(al, bh[nf], acc[mf][nf], 0, 0, 0);
            }
        }
        __syncthreads();
    }

    // epilogue: D layout col=lane&15 (px), row=(lane>>4)*4+j
    int h = 2 * hB + wn;
    float lmp[4] = {0.f, 0.f, 0.f, 0.f};
#pragma unroll
    for (int mf = 0; mf < 7; ++mf) {
        int base = wm * 112 + mf * 16;
        int r0 = base + c4l * 4;
        if (base < 128) {
#pragma unroll
            for (int nf = 0; nf < 4; ++nf) {
                int x = nf * 16 + lrow;
                float* dst = qt + ((size_t)b * 128 + r0) * HW + h * 64 + x;
                f32x4 v = acc[mf][nf];
#pragma unroll
                for (int j = 0; j < 4; ++j)
                    dst[(size_t)j * HW] = v[j] + biasS[r0 + j];
            }
        } else {
            float b0 = biasS[r0], b1 = biasS[r0 + 1], b2 = biasS[r0 + 2], b3 = biasS[r0 + 3];
#pragma unroll
            for (int nf = 0; nf < 4; ++nf) {
                f32x4 v = acc[mf][nf];
                lmp[nf] += (v[0] + b0) * (v[1] + b1) + (v[2] + b2) * (v[3] + b3);
            }
        }
    }
    if (wm != 0) {
#pragma unroll
        for (int nf = 0; nf < 4; ++nf) {
            lmp[nf] += __shfl_xor(lmp[nf], 16);
            lmp[nf] += __shfl_xor(lmp[nf], 32);
        }
        if (c4l == 0) {
#pragma unroll
            for (int nf = 0; nf < 4; ++nf)
                atomicAdd(&lmAcc[wn][nf * 16 + lrow], lmp[nf]);
        }
    }
    __syncthreads();
    if (t < 128) {
        int wn2 = t >> 6, px = t & 63;
        lm[b * HW + (2 * hB + wn2) * 64 + px] = lmAcc[wn2][px];
    }
#undef STAGE1
}

// ---------------- K2m: implicit-GEMM MFMA 3x3 conv (hi plane only) ----------------
__global__ __launch_bounds__(256, 1) void k2m(const unsigned short* __restrict__ msP,
                                              const unsigned short* __restrict__ Wb,
                                              const float* __restrict__ Wv_b,
                                              float* __restrict__ vals) {
    __shared__ unsigned short Bs[2][8448];   // [buf][(r*4+c4)*66 + x][8ci]
    __shared__ float biasS[128];
    int t = threadIdx.x;
    int lane = t & 63, wid = t >> 6;
    int wm = wid >> 1, wn = wid & 1;
    int b = blockIdx.x >> 5, hB = blockIdx.x & 31;
    int c4l = lane >> 4, lrow = lane & 15;
    if (t < 128) biasS[t] = Wv_b[t];

    f32x4 acc[4][4];
#pragma unroll
    for (int mf = 0; mf < 4; ++mf)
#pragma unroll
        for (int nf = 0; nf < 4; ++nf) acc[mf][nf] = (f32x4){0.f, 0.f, 0.f, 0.f};

    const bf16x8* Wbp = (const bf16x8*)Wb;

#define STAGE(bufv, sv) do {                                                        \
    for (int iter = 0; iter < 5; ++iter) {                                          \
        int q0 = iter * 256 + (wid << 6);                                           \
        int q = q0 + lane;                                                          \
        if (q < 1056) {                                                             \
            int r = q / 264; int rem = q - r * 264;                                 \
            int c4 = rem / 66; int x = rem - c4 * 66;                               \
            int y = 2 * hB + r;                                                     \
            const unsigned short* gp = msP +                                        \
                (((((size_t)b * 66 + y) * 32) + ((sv) * 4 + c4)) * 66 + x) * 8;     \
            unsigned short* lp = &Bs[bufv][q0 * 8];                                 \
            __builtin_amdgcn_global_load_lds(                                       \
                (const __attribute__((address_space(1))) void*)gp,                  \
                (__attribute__((address_space(3))) void*)lp, 16, 0, 0);             \
        }                                                                           \
    }                                                                               \
} while (0)

    STAGE(0, 0);
    __syncthreads();

    for (int s = 0; s < 8; ++s) {
        int cur = s & 1;
        if (s < 7) STAGE(cur ^ 1, s + 1);
#pragma unroll
        for (int khw = 0; khw < 9; ++khw) {
            int kh = khw / 3, kw = khw - 3 * (khw / 3);
            bf16x8 a[4];
#pragma unroll
            for (int mf = 0; mf < 4; ++mf)
                a[mf] = Wbp[((khw * 8 + s) * 4 + c4l) * 128 + wm * 64 + mf * 16 + lrow];
            bf16x8 bf[4];
#pragma unroll
            for (int nf = 0; nf < 4; ++nf) {
                int chunk = ((wn + kh) * 4 + c4l) * 66 + nf * 16 + lrow + kw;
                bf[nf] = *(const bf16x8*)&Bs[cur][chunk * 8];
            }
#pragma unroll
            for (int mf = 0; mf < 4; ++mf)
#pragma unroll
                for (int nf = 0; nf < 4; ++nf)
                    acc[mf][nf] = __builtin_amdgcn_mfma_f32_16x16x32_bf16(
                        a[mf], bf[nf], acc[mf][nf], 0, 0, 0);
        }
        __syncthreads();
    }

    int h = 2 * hB + wn;
#pragma unroll
    for (int mf = 0; mf < 4; ++mf) {
        int co0 = wm * 64 + mf * 16 + c4l * 4;
#pragma unroll
        for (int nf = 0; nf < 4; ++nf) {
            int x = nf * 16 + lrow;
            float* dst = vals + (((size_t)b * 128 + co0) * HW) + h * 64 + x;
            f32x4 v = acc[mf][nf];
#pragma unroll
            for (int j = 0; j < 4; ++j)
                dst[(size_t)j * HW] = v[j] + biasS[co0 + j];
        }
    }
#undef STAGE
}

// ---------------- K3: register-resident logits -> softmax -> combine ----------------
// grid 2048 = b(8) x y(128) x xh(2); block 256: xg = t&15 (4x each), cq = t>>4 (8c each)
__global__ __launch_bounds__(256, 2) void k3(
    const float* __restrict__ ctx, const float* __restrict__ qt,
    const float* __restrict__ vals, const float* __restrict__ lm,
    float* __restrict__ out) {
    __shared__ float part[4][3][64];
    __shared__ float attnS[4][64];
    int t = threadIdx.x;
    int lane = t & 63, wv = t >> 6;
    int xg = t & 15, cq = t >> 4;
    int blk = blockIdx.x;
    int b = blk >> 8, y = (blk >> 1) & 127, xh = blk & 1;
    int h = y >> 1;
    int x0 = xh * 64 + xg * 4;
    int p0 = xh * 32 + xg * 2;

    float2 qv[8], vv[8];
    const float* qbase = qt + ((size_t)b * 128 + cq * 8) * HW + h * 64 + p0;
    const float* vbase = vals + ((size_t)b * 128 + cq * 8) * HW + h * 64 + p0;
#pragma unroll
    for (int j = 0; j < 8; ++j) {
        qv[j] = *(const float2*)&qbase[(size_t)j * HW];
        vv[j] = *(const float2*)&vbase[(size_t)j * HW];
    }
    float4 cx[3][8];
#pragma unroll
    for (int n = 0; n < 3; ++n) {
        const float* cb = ctx + ((size_t)(n * 8 + b) * 128 + cq * 8) * YX + (size_t)y * 128 + x0;
#pragma unroll
        for (int j = 0; j < 8; ++j) cx[n][j] = *(const float4*)&cb[(size_t)j * YX];
    }
    float lp[3][4];
#pragma unroll
    for (int n = 0; n < 3; ++n) {
#pragma unroll
        for (int xl = 0; xl < 4; ++xl) lp[n][xl] = 0.f;
#pragma unroll
        for (int j = 0; j < 8; ++j) {
            lp[n][0] += cx[n][j].x * qv[j].x;
            lp[n][1] += cx[n][j].y * qv[j].x;
            lp[n][2] += cx[n][j].z * qv[j].y;
            lp[n][3] += cx[n][j].w * qv[j].y;
        }
    }
    // reduce over the wave's 4 cq groups (lanes differ in bits 4,5)
#pragma unroll
    for (int n = 0; n < 3; ++n)
#pragma unroll
        for (int xl = 0; xl < 4; ++xl) {
            float v = lp[n][xl];
            v += __shfl_xor(v, 16);
            v += __shfl_xor(v, 32);
            lp[n][xl] = v;
        }
    if (lane < 16) {
#pragma unroll
        for (int n = 0; n < 3; ++n)
#pragma unroll
            for (int xl = 0; xl < 4; ++xl)
                part[wv][n][lane * 4 + xl] = lp[n][xl];
    }
    __syncthreads();
    if (t < 64) {
        float l0 = part[0][0][t] + part[1][0][t] + part[2][0][t] + part[3][0][t];
        float l1 = part[0][1][t] + part[1][1][t] + part[2][1][t] + part[3][1][t];
        float l2 = part[0][2][t] + part[1][2][t] + part[2][2][t] + part[3][2][t];
        float l3 = lm[(size_t)b * HW + h * 64 + xh * 32 + (t >> 1)];
        float m = fmaxf(fmaxf(l0, l1), fmaxf(l2, l3));
        float e0 = __expf(l0 - m), e1 = __expf(l1 - m), e2 = __expf(l2 - m), e3 = __expf(l3 - m);
        float inv = 1.f / (e0 + e1 + e2 + e3);
        attnS[0][t] = e0 * inv; attnS[1][t] = e1 * inv;
        attnS[2][t] = e2 * inv; attnS[3][t] = e3 * inv;
    }
    __syncthreads();
    float a0[4], a1[4], a2[4], a3[4];
#pragma unroll
    for (int xl = 0; xl < 4; ++xl) {
        a0[xl] = attnS[0][xg * 4 + xl];
        a1[xl] = attnS[1][xg * 4 + xl];
        a2[xl] = attnS[2][xg * 4 + xl];
        a3[xl] = attnS[3][xg * 4 + xl];
    }
    float* obase = out + ((size_t)b * 128 + cq * 8) * YX + (size_t)y * 128 + x0;
#pragma unroll
    for (int j = 0; j < 8; ++j) {
        float4 o;
        o.x = a3[0] * vv[j].x + a0[0] * cx[0][j].x + a1[0] * cx[1][j].x + a2[0] * cx[2][j].x;
        o.y = a3[1] * vv[j].x + a0[1] * cx[0][j].y + a1[1] * cx[1][j].y + a2[1] * cx[2][j].y;
        o.z = a3[2] * vv[j].y + a0[2] * cx[0][j].z + a1[2] * cx[1][j].z + a2[2] * cx[2][j].z;
        o.w = a3[3] * vv[j].y + a0[3] * cx[0][j].w + a1[3] * cx[1][j].w + a2[3] * cx[2][j].w;
        *(float4*)&obase[(size_t)j * YX] = o;
    }
}

extern "C" void kernel_launch(void* const* d_in, const int* in_sizes, int n_in,
                              void* d_out, int out_size, void* d_ws, size_t ws_size,
                              hipStream_t stream) {
    const float* ctx  = (const float*)d_in[0];
    const float* ms   = (const float*)d_in[1];
    const float* Wc_w = (const float*)d_in[2];
    const float* Wc_b = (const float*)d_in[3];
    const float* Wf_w = (const float*)d_in[4];
    const float* Wf_b = (const float*)d_in[5];
    const float* Wk_w = (const float*)d_in[6];
    const float* Wk_b = (const float*)d_in[7];
    const float* Wv_w = (const float*)d_in[8];
    const float* Wv_b = (const float*)d_in[9];
    float* out = (float*)d_out;
    float* ws = (float*)d_ws;
    float* qt     = ws + WS_QT;
    float* vals   = ws + WS_VALS;
    float* bias448= ws + WS_BIAS;
    float* lmp    = ws + WS_LM;
    float* WqtT   = ws + WS_WQTT;
    float* bqt    = ws + WS_BQT;
    float* wqb    = ws + WS_WQB;
    float* bqb    = ws + WS_BQB;
    unsigned short* Wallp  = (unsigned short*)(ws + WS_WALL);
    unsigned short* Wallop = (unsigned short*)(ws + WS_BIAS + 1024);  // 57344 ushorts in bias slot
    unsigned short* msPp   = (unsigned short*)(ws + WS_MSP);
    unsigned short* msLop  = (unsigned short*)(ws + WS_VALS);         // dead before k2m writes vals
    unsigned short* Wbp    = (unsigned short*)(ws + WS_WB);

    hipLaunchKernelGGL(k2z, dim3(260), dim3(256), 0, stream, msPp);
    hipLaunchKernelGGL(k0b, dim3(130), dim3(256), 0, stream, Wc_w, Wc_b, Wf_w, Wf_b,
                       WqtT, bqt, wqb, bqb);
    hipLaunchKernelGGL(k0c, dim3(1152), dim3(256), 0, stream, Wv_w, Wbp);
    hipLaunchKernelGGL(k0d, dim3(448), dim3(256), 0, stream, WqtT, bqt, Wf_w, Wf_b,
                       Wk_w, Wk_b, wqb, bqb, Wallp, Wallop, bias448);
    hipLaunchKernelGGL(k2p, dim3(4096), dim3(256), 0, stream, ms, msPp, msLop);
    hipLaunchKernelGGL(k1m, dim3(256), dim3(512), 0, stream, msPp, msLop, Wallp, Wallop,
                       bias448, qt, lmp);
    hipLaunchKernelGGL(k2m, dim3(256), dim3(256), 0, stream, msPp, Wbp, Wv_b, vals);
    hipLaunchKernelGGL(k3, dim3(2048), dim3(256), 0, stream, ctx, qt, vals, lmp, out);
}

// Round 5
// 153.364 us; speedup vs baseline: 4.0061x; 1.1367x over previous
//
#include <hip/hip_runtime.h>

#define NCTX 3
#define B 8
#define CC 128
#define CF 256
#define H 64
#define W 64
#define HW 4096
#define YX 16384   // (2H)*(2W)

// workspace layout (float offsets)
#define WS_QT    0          // B*CC*HW = 4194304
#define WS_VALS  4194304    // B*CC*HW floats; ALSO aliased as msLo (8388608 ushorts) before k2m
#define WS_BIAS  8388608    // bias448 (448 floats)
#define WS_LM    8421376    // B*HW
#define WS_WALL  8454144    // bf16 Wall hi: 8*4*448*8 = 114688 ushorts = 57344 floats
#define WS_MSP   8552960    // bf16 msP hi: 8*66*32*66*8 = 8921088 ushorts
#define WS_WB    13013504   // bf16 Wb: 9*8*4*128*8 = 294912 ushorts = 147456 floats
#define WS_WALLO 13160960   // bf16 Wall lo: 114688 ushorts = 57344 floats (end 13218304)

typedef __attribute__((ext_vector_type(8))) short bf16x8;
typedef __attribute__((ext_vector_type(4))) float f32x4;
typedef __attribute__((ext_vector_type(8))) unsigned short u16x8;

__device__ __forceinline__ unsigned short f2b(float f) {
    union { float f; unsigned u; } c; c.f = f;
    unsigned u = c.u + 0x7FFFu + ((c.u >> 16) & 1u);
    return (unsigned short)(u >> 16);
}
__device__ __forceinline__ float b2f(unsigned short u) {
    union { unsigned u; float f; } c; c.u = ((unsigned)u) << 16;
    return c.f;
}

// ---------------- K0: all prepasses merged (block-range dispatch) ----------------
// blk [0,448):    Wall hi/lo + bias448 (direct dots, absorbs old k0b)
// blk [448,1600): Wb conv-weight pack
// blk [1600,1860): msP halo zero
__global__ void k0(const float* __restrict__ Wc_w, const float* __restrict__ Wc_b,
                   const float* __restrict__ Wf_w, const float* __restrict__ Wf_b,
                   const float* __restrict__ Wk_w, const float* __restrict__ Wk_b,
                   const float* __restrict__ Wv,
                   unsigned short* __restrict__ Wall, unsigned short* __restrict__ Wallo,
                   float* __restrict__ bias448, unsigned short* __restrict__ Wb,
                   unsigned short* __restrict__ msP) {
    int blk = blockIdx.x;
    int t = threadIdx.x;
    if (blk < 448) {
        int o = blk * 256 + t;                    // 114688
        int ci8 = o & 7;
        int idx = o >> 3;                         // sc4*448 + row
        int row = idx % 448;
        int sc4 = idx / 448;                      // s*4 + c4
        int f = (sc4 >> 2) * 32 + (sc4 & 3) * 8 + ci8;
        float w;
        if (row < 128) {
            float s = 0.f;
            for (int o2 = 0; o2 < 128; ++o2) s += Wc_w[o2 * 128 + row] * Wf_w[o2 * 256 + f];
            w = s;
        } else if (row < 384) {
            int p = (row - 128) >> 1;
            w = (row & 1) ? Wk_w[p * 256 + f] : Wf_w[p * 256 + f];
        } else if (row == 384) {
            float s = 0.f;
            for (int o2 = 0; o2 < 128; ++o2) s += Wc_b[o2] * Wf_w[o2 * 256 + f];
            w = s;
        } else w = 0.f;
        unsigned short hi = f2b(w);
        Wall[o] = hi;
        Wallo[o] = f2b(w - b2f(hi));
        if (o < 448) {
            float bb;
            if (o < 128) {
                float s = 0.f;
                for (int o2 = 0; o2 < 128; ++o2) s += Wc_w[o2 * 128 + o] * Wf_b[o2];
                bb = s;
            } else if (o < 384) {
                int p = (o - 128) >> 1;
                bb = (o & 1) ? Wk_b[p] : Wf_b[p];
            } else if (o == 384) {
                float s = 0.f;
                for (int o2 = 0; o2 < 128; ++o2) s += Wc_b[o2] * Wf_b[o2];
                bb = s;
            } else if (o == 385) bb = -1.f;
            else bb = 0.f;
            bias448[o] = bb;
        }
    } else if (blk < 1600) {
        int o = (blk - 448) * 256 + t;            // 294912
        int ci8 = o & 7;
        int co  = (o >> 3) & 127;
        int c4  = (o >> 10) & 3;
        int s   = (o >> 12) & 7;
        int khw = o >> 15;                        // [0,9)
        int ci  = s * 32 + c4 * 8 + ci8;
        int kh  = khw / 3, kw = khw - kh * 3;
        Wb[o] = f2b(Wv[((co * 256 + ci) * 3 + kh) * 3 + kw]);
    } else {
        int i = (blk - 1600) * 256 + t;           // 66560 exactly
        if (i < 66560) {
            size_t off;
            if (i < 33792) {          // rows y=0,65: 8b*2*32g*66x
                int x = i % 66; int r = i / 66;
                int g = r & 31, rowi = (r >> 5) & 1, b = r >> 6;
                off = ((((size_t)b * 66 + rowi * 65) * 32) + g) * 66 + x;
            } else {                  // cols x=0,65 for y=1..64
                int k = i - 33792;
                int xi = k & 1; int g = (k >> 1) & 31; int y1 = (k >> 6) & 63; int b = k >> 12;
                off = ((((size_t)b * 66 + (y1 + 1)) * 32) + g) * 66 + xi * 65;
            }
            *(u16x8*)&msP[off * 8] = (u16x8){0, 0, 0, 0, 0, 0, 0, 0};
        }
    }
}

// ---------------- K2p: ms -> padded bf16 msP (hi) + unpadded residual msLo ----------
__global__ __launch_bounds__(256) void k2p(const float* __restrict__ ms,
                                           unsigned short* __restrict__ msP,
                                           unsigned short* __restrict__ msLo) {
    __shared__ float Ls[32][65];
    int t = threadIdx.x;
    int blk = blockIdx.x;          // 4096 = 8b * 64h * 8s
    int s = blk & 7;
    int h = (blk >> 3) & 63;
    int b = blk >> 9;
    const float* src = ms + ((size_t)b * 256 + s * 32) * HW + h * 64;
    for (int l = t; l < 2048; l += 256) {
        int ci = l >> 6, w = l & 63;
        Ls[ci][w] = src[ci * HW + w];
    }
    __syncthreads();
    int w = t & 63, gi = t >> 6;   // gi in [0,4)
    u16x8 vh, vl;
#pragma unroll
    for (int j = 0; j < 8; ++j) {
        float f = Ls[gi * 8 + j][w];
        unsigned short hb = f2b(f);
        vh[j] = hb;
        vl[j] = f2b(f - b2f(hb));
    }
    size_t offH = ((((size_t)b * 66 + (h + 1)) * 32) + (s * 4 + gi)) * 66 + (w + 1);
    *(u16x8*)&msP[offH * 8] = vh;
    size_t offL = ((((size_t)b * 64 + h) * 32) + (s * 4 + gi)) * 64 + w;
    *(u16x8*)&msLo[offL * 8] = vl;
}

// ---------------- K1m: fused qt/q/mkey/lm, split-bf16 MFMA, one row per block -------
// grid 512 = 8b*64h; block 512 = 8 waves: wm=wid>>1 in [0,4) (112 rows), wn=wid&1 (x-half)
__global__ __launch_bounds__(512, 4) void k1m(const unsigned short* __restrict__ msP,
                                              const unsigned short* __restrict__ msLo,
                                              const unsigned short* __restrict__ Wall,
                                              const unsigned short* __restrict__ Wallo,
                                              const float* __restrict__ bias448,
                                              float* __restrict__ qt, float* __restrict__ lm) {
    __shared__ unsigned short Bs[2][2][4][64][8];  // [buf][plane][c4][x][ci8] = 16 KB
    __shared__ float biasS[448];
    __shared__ float lmAcc[64];
    int t = threadIdx.x;
    int lane = t & 63, wid = t >> 6;
    int wm = wid >> 1, wn = wid & 1;
    int b = blockIdx.x >> 6, h = blockIdx.x & 63;
    int c4l = lane >> 4, lrow = lane & 15;
    for (int i = t; i < 448; i += 512) biasS[i] = bias448[i];
    if (t < 64) lmAcc[t] = 0.f;

    f32x4 acc[7][2];
#pragma unroll
    for (int mf = 0; mf < 7; ++mf)
#pragma unroll
        for (int nf = 0; nf < 2; ++nf) acc[mf][nf] = (f32x4){0.f, 0.f, 0.f, 0.f};

    const bf16x8* Whip = (const bf16x8*)Wall;
    const bf16x8* Wlop = (const bf16x8*)Wallo;

#define STAGE1(bufv, sv) do {                                                       \
    int pl_ = wid >> 2, c4_ = wid & 3;                                              \
    if (pl_ == 0) {                                                                 \
        const unsigned short* gph = msP +                                           \
            (((((size_t)b * 66 + (h + 1)) * 32) + ((sv) * 4 + c4_)) * 66            \
             + (lane + 1)) * 8;                                                     \
        __builtin_amdgcn_global_load_lds(                                           \
            (const __attribute__((address_space(1))) void*)gph,                     \
            (__attribute__((address_space(3))) void*)&Bs[bufv][0][c4_][0][0],       \
            16, 0, 0);                                                              \
    } else {                                                                        \
        const unsigned short* gpl = msLo +                                          \
            (((((size_t)b * 64 + h) * 32) + ((sv) * 4 + c4_)) * 64 + lane) * 8;     \
        __builtin_amdgcn_global_load_lds(                                           \
            (const __attribute__((address_space(1))) void*)gpl,                     \
            (__attribute__((address_space(3))) void*)&Bs[bufv][1][c4_][0][0],       \
            16, 0, 0);                                                              \
    }                                                                               \
} while (0)

    STAGE1(0, 0);
    __syncthreads();

    for (int s = 0; s < 8; ++s) {
        int cur = s & 1;
        if (s < 7) STAGE1(cur ^ 1, s + 1);
        bf16x8 bh[2], bl[2];
#pragma unroll
        for (int nf = 0; nf < 2; ++nf) {
            int x = wn * 32 + nf * 16 + lrow;
            bh[nf] = *(const bf16x8*)&Bs[cur][0][c4l][x][0];
            bl[nf] = *(const bf16x8*)&Bs[cur][1][c4l][x][0];
        }
#pragma unroll
        for (int mf = 0; mf < 7; ++mf) {
            size_t widx = (size_t)(s * 4 + c4l) * 448 + wm * 112 + mf * 16 + lrow;
            bf16x8 ah = Whip[widx];
            bf16x8 al = Wlop[widx];
#pragma unroll
            for (int nf = 0; nf < 2; ++nf) {
                acc[mf][nf] = __builtin_amdgcn_mfma_f32_16x16x32_bf16(ah, bh[nf], acc[mf][nf], 0, 0, 0);
                acc[mf][nf] = __builtin_amdgcn_mfma_f32_16x16x32_bf16(ah, bl[nf], acc[mf][nf], 0, 0, 0);
                acc[mf][nf] = __builtin_amdgcn_mfma_f32_16x16x32_bf16(al, bh[nf], acc[mf][nf], 0, 0, 0);
            }
        }
        __syncthreads();
    }

    // epilogue: D layout col=lane&15 (px), row=(lane>>4)*4+j
    int px0 = wn * 32;
    float lmp[2] = {0.f, 0.f};
#pragma unroll
    for (int mf = 0; mf < 7; ++mf) {
        int base = wm * 112 + mf * 16;
        int r0 = base + c4l * 4;
        if (base < 128) {
#pragma unroll
            for (int nf = 0; nf < 2; ++nf) {
                int x = px0 + nf * 16 + lrow;
                float* dst = qt + ((size_t)b * 128 + r0) * HW + h * 64 + x;
                f32x4 v = acc[mf][nf];
#pragma unroll
                for (int j = 0; j < 4; ++j)
                    dst[(size_t)j * HW] = v[j] + biasS[r0 + j];
            }
        } else {
            float b0 = biasS[r0], b1 = biasS[r0 + 1], b2 = biasS[r0 + 2], b3 = biasS[r0 + 3];
#pragma unroll
            for (int nf = 0; nf < 2; ++nf) {
                f32x4 v = acc[mf][nf];
                lmp[nf] += (v[0] + b0) * (v[1] + b1) + (v[2] + b2) * (v[3] + b3);
            }
        }
    }
    if (wm != 0) {
#pragma unroll
        for (int nf = 0; nf < 2; ++nf) {
            lmp[nf] += __shfl_xor(lmp[nf], 16);
            lmp[nf] += __shfl_xor(lmp[nf], 32);
        }
        if (c4l == 0) {
#pragma unroll
            for (int nf = 0; nf < 2; ++nf)
                atomicAdd(&lmAcc[px0 + nf * 16 + lrow], lmp[nf]);
        }
    }
    __syncthreads();
    if (t < 64) lm[b * HW + h * 64 + t] = lmAcc[t];
#undef STAGE1
}

// ---------------- K2m: implicit-GEMM MFMA 3x3 conv, one row per block ----------------
// grid 512 = 8b*64h; block 256 = 4 waves: wm=wid in [0,4) (32 co each), nf covers 64 px
__global__ __launch_bounds__(256, 4) void k2m(const unsigned short* __restrict__ msP,
                                              const unsigned short* __restrict__ Wb,
                                              const float* __restrict__ Wv_b,
                                              float* __restrict__ vals) {
    __shared__ unsigned short Bs[2][6336];   // [buf][(r*4+c4)*66 + x][8ci], r in [0,3)
    __shared__ float biasS[128];
    int t = threadIdx.x;
    int lane = t & 63, wid = t >> 6;
    int wm = wid;
    int b = blockIdx.x >> 6, h = blockIdx.x & 63;
    int c4l = lane >> 4, lrow = lane & 15;
    if (t < 128) biasS[t] = Wv_b[t];

    f32x4 acc[2][4];
#pragma unroll
    for (int mf = 0; mf < 2; ++mf)
#pragma unroll
        for (int nf = 0; nf < 4; ++nf) acc[mf][nf] = (f32x4){0.f, 0.f, 0.f, 0.f};

    const bf16x8* Wbp = (const bf16x8*)Wb;

#define STAGE(bufv, sv) do {                                                        \
    for (int iter = 0; iter < 4; ++iter) {                                          \
        int q0 = iter * 256 + (wid << 6);                                           \
        int q = q0 + lane;                                                          \
        if (q < 792) {                                                              \
            int rc = q / 66; int x = q - rc * 66;                                   \
            int r = rc >> 2, c4 = rc & 3;                                           \
            int y = h + r;                          /* msP rows h-1..h+1 */         \
            const unsigned short* gp = msP +                                        \
                (((((size_t)b * 66 + y) * 32) + ((sv) * 4 + c4)) * 66 + x) * 8;     \
            unsigned short* lp = &Bs[bufv][q0 * 8];                                 \
            __builtin_amdgcn_global_load_lds(                                       \
                (const __attribute__((address_space(1))) void*)gp,                  \
                (__attribute__((address_space(3))) void*)lp, 16, 0, 0);             \
        }                                                                           \
    }                                                                               \
} while (0)

    STAGE(0, 0);
    __syncthreads();

    for (int s = 0; s < 8; ++s) {
        int cur = s & 1;
        if (s < 7) STAGE(cur ^ 1, s + 1);
#pragma unroll
        for (int khw = 0; khw < 9; ++khw) {
            int kh = khw / 3, kw = khw - 3 * (khw / 3);
            bf16x8 a[2];
#pragma unroll
            for (int mf = 0; mf < 2; ++mf)
                a[mf] = Wbp[((khw * 8 + s) * 4 + c4l) * 128 + wm * 32 + mf * 16 + lrow];
            bf16x8 bf[4];
#pragma unroll
            for (int nf = 0; nf < 4; ++nf) {
                int chunk = (kh * 4 + c4l) * 66 + nf * 16 + lrow + kw;
                bf[nf] = *(const bf16x8*)&Bs[cur][chunk * 8];
            }
#pragma unroll
            for (int mf = 0; mf < 2; ++mf)
#pragma unroll
                for (int nf = 0; nf < 4; ++nf)
                    acc[mf][nf] = __builtin_amdgcn_mfma_f32_16x16x32_bf16(
                        a[mf], bf[nf], acc[mf][nf], 0, 0, 0);
        }
        __syncthreads();
    }

    // epilogue: D layout col=lane&15 (px), row=(lane>>4)*4+j (co)
#pragma unroll
    for (int mf = 0; mf < 2; ++mf) {
        int co0 = wm * 32 + mf * 16 + c4l * 4;
#pragma unroll
        for (int nf = 0; nf < 4; ++nf) {
            int x = nf * 16 + lrow;
            float* dst = vals + (((size_t)b * 128 + co0) * HW) + h * 64 + x;
            f32x4 v = acc[mf][nf];
#pragma unroll
            for (int j = 0; j < 4; ++j)
                dst[(size_t)j * HW] = v[j] + biasS[co0 + j];
        }
    }
#undef STAGE
}

// ---------------- K3: register-resident logits -> softmax -> combine ----------------
// grid 2048 = b(8) x y(128) x xh(2); block 256: xg = t&15 (4x each), cq = t>>4 (8c each)
__global__ __launch_bounds__(256, 2) void k3(
    const float* __restrict__ ctx, const float* __restrict__ qt,
    const float* __restrict__ vals, const float* __restrict__ lm,
    float* __restrict__ out) {
    __shared__ float part[4][3][64];
    __shared__ float attnS[4][64];
    int t = threadIdx.x;
    int lane = t & 63, wv = t >> 6;
    int xg = t & 15, cq = t >> 4;
    int blk = blockIdx.x;
    int b = blk >> 8, y = (blk >> 1) & 127, xh = blk & 1;
    int h = y >> 1;
    int x0 = xh * 64 + xg * 4;
    int p0 = xh * 32 + xg * 2;

    float2 qv[8], vv[8];
    const float* qbase = qt + ((size_t)b * 128 + cq * 8) * HW + h * 64 + p0;
    const float* vbase = vals + ((size_t)b * 128 + cq * 8) * HW + h * 64 + p0;
#pragma unroll
    for (int j = 0; j < 8; ++j) {
        qv[j] = *(const float2*)&qbase[(size_t)j * HW];
        vv[j] = *(const float2*)&vbase[(size_t)j * HW];
    }
    float4 cx[3][8];
#pragma unroll
    for (int n = 0; n < 3; ++n) {
        const float* cb = ctx + ((size_t)(n * 8 + b) * 128 + cq * 8) * YX + (size_t)y * 128 + x0;
#pragma unroll
        for (int j = 0; j < 8; ++j) cx[n][j] = *(const float4*)&cb[(size_t)j * YX];
    }
    float lp[3][4];
#pragma unroll
    for (int n = 0; n < 3; ++n) {
#pragma unroll
        for (int xl = 0; xl < 4; ++xl) lp[n][xl] = 0.f;
#pragma unroll
        for (int j = 0; j < 8; ++j) {
            lp[n][0] += cx[n][j].x * qv[j].x;
            lp[n][1] += cx[n][j].y * qv[j].x;
            lp[n][2] += cx[n][j].z * qv[j].y;
            lp[n][3] += cx[n][j].w * qv[j].y;
        }
    }
#pragma unroll
    for (int n = 0; n < 3; ++n)
#pragma unroll
        for (int xl = 0; xl < 4; ++xl) {
            float v = lp[n][xl];
            v += __shfl_xor(v, 16);
            v += __shfl_xor(v, 32);
            lp[n][xl] = v;
        }
    if (lane < 16) {
#pragma unroll
        for (int n = 0; n < 3; ++n)
#pragma unroll
            for (int xl = 0; xl < 4; ++xl)
                part[wv][n][lane * 4 + xl] = lp[n][xl];
    }
    __syncthreads();
    if (t < 64) {
        float l0 = part[0][0][t] + part[1][0][t] + part[2][0][t] + part[3][0][t];
        float l1 = part[0][1][t] + part[1][1][t] + part[2][1][t] + part[3][1][t];
        float l2 = part[0][2][t] + part[1][2][t] + part[2][2][t] + part[3][2][t];
        float l3 = lm[(size_t)b * HW + h * 64 + xh * 32 + (t >> 1)];
        float m = fmaxf(fmaxf(l0, l1), fmaxf(l2, l3));
        float e0 = __expf(l0 - m), e1 = __expf(l1 - m), e2 = __expf(l2 - m), e3 = __expf(l3 - m);
        float inv = 1.f / (e0 + e1 + e2 + e3);
        attnS[0][t] = e0 * inv; attnS[1][t] = e1 * inv;
        attnS[2][t] = e2 * inv; attnS[3][t] = e3 * inv;
    }
    __syncthreads();
    float a0[4], a1[4], a2[4], a3[4];
#pragma unroll
    for (int xl = 0; xl < 4; ++xl) {
        a0[xl] = attnS[0][xg * 4 + xl];
        a1[xl] = attnS[1][xg * 4 + xl];
        a2[xl] = attnS[2][xg * 4 + xl];
        a3[xl] = attnS[3][xg * 4 + xl];
    }
    float* obase = out + ((size_t)b * 128 + cq * 8) * YX + (size_t)y * 128 + x0;
#pragma unroll
    for (int j = 0; j < 8; ++j) {
        float4 o;
        o.x = a3[0] * vv[j].x + a0[0] * cx[0][j].x + a1[0] * cx[1][j].x + a2[0] * cx[2][j].x;
        o.y = a3[1] * vv[j].x + a0[1] * cx[0][j].y + a1[1] * cx[1][j].y + a2[1] * cx[2][j].y;
        o.z = a3[2] * vv[j].y + a0[2] * cx[0][j].z + a1[2] * cx[1][j].z + a2[2] * cx[2][j].z;
        o.w = a3[3] * vv[j].y + a0[3] * cx[0][j].w + a1[3] * cx[1][j].w + a2[3] * cx[2][j].w;
        *(float4*)&obase[(size_t)j * YX] = o;
    }
}

extern "C" void kernel_launch(void* const* d_in, const int* in_sizes, int n_in,
                              void* d_out, int out_size, void* d_ws, size_t ws_size,
                              hipStream_t stream) {
    const float* ctx  = (const float*)d_in[0];
    const float* ms   = (const float*)d_in[1];
    const float* Wc_w = (const float*)d_in[2];
    const float* Wc_b = (const float*)d_in[3];
    const float* Wf_w = (const float*)d_in[4];
    const float* Wf_b = (const float*)d_in[5];
    const float* Wk_w = (const float*)d_in[6];
    const float* Wk_b = (const float*)d_in[7];
    const float* Wv_w = (const float*)d_in[8];
    const float* Wv_b = (const float*)d_in[9];
    float* out = (float*)d_out;
    float* ws = (float*)d_ws;
    float* qt      = ws + WS_QT;
    float* vals    = ws + WS_VALS;
    float* bias448 = ws + WS_BIAS;
    float* lmp     = ws + WS_LM;
    unsigned short* Wallp  = (unsigned short*)(ws + WS_WALL);
    unsigned short* Wallop = (unsigned short*)(ws + WS_WALLO);
    unsigned short* msPp   = (unsigned short*)(ws + WS_MSP);
    unsigned short* msLop  = (unsigned short*)(ws + WS_VALS);   // dead before k2m writes vals
    unsigned short* Wbp    = (unsigned short*)(ws + WS_WB);

    hipLaunchKernelGGL(k0, dim3(1860), dim3(256), 0, stream, Wc_w, Wc_b, Wf_w, Wf_b,
                       Wk_w, Wk_b, Wv_w, Wallp, Wallop, bias448, Wbp, msPp);
    hipLaunchKernelGGL(k2p, dim3(4096), dim3(256), 0, stream, ms, msPp, msLop);
    hipLaunchKernelGGL(k1m, dim3(512), dim3(512), 0, stream, msPp, msLop, Wallp, Wallop,
                       bias448, qt, lmp);
    hipLaunchKernelGGL(k2m, dim3(512), dim3(256), 0, stream, msPp, Wbp, Wv_b, vals);
    hipLaunchKernelGGL(k3, dim3(2048), dim3(256), 0, stream, ctx, qt, vals, lmp, out);
}

// Round 6
// 146.319 us; speedup vs baseline: 4.1990x; 1.0481x over previous
//
#include <hip/hip_runtime.h>

#define NCTX 3
#define B 8
#define CC 128
#define CF 256
#define H 64
#define W 64
#define HW 4096
#define YX 16384   // (2H)*(2W)

// workspace layout (float offsets)
#define WS_QT    0          // B*CC*HW = 4194304
#define WS_VALS  4194304    // B*CC*HW fp32 (no longer aliased)
#define WS_BIAS  8388608    // bias448 (448 floats)
#define WS_LM    8421376    // B*HW
#define WS_WALL  8454144    // bf16 Wall hi: 8*4*448*8 = 114688 ushorts = 57344 floats
#define WS_MSP   8552960    // bf16 msP hi: 8*66*32*66*8 = 8921088 ushorts
#define WS_WB    13013504   // bf16 Wb: 9*8*4*128*8 = 294912 ushorts = 147456 floats
#define WS_WALLO 13160960   // bf16 Wall lo: 114688 ushorts (end 13218304)

typedef __attribute__((ext_vector_type(8))) short bf16x8;
typedef __attribute__((ext_vector_type(4))) float f32x4;
typedef __attribute__((ext_vector_type(8))) unsigned short u16x8;

__device__ __forceinline__ unsigned short f2b(float f) {
    union { float f; unsigned u; } c; c.f = f;
    unsigned u = c.u + 0x7FFFu + ((c.u >> 16) & 1u);
    return (unsigned short)(u >> 16);
}
__device__ __forceinline__ float b2f(unsigned short u) {
    union { unsigned u; float f; } c; c.u = ((unsigned)u) << 16;
    return c.f;
}

// ---------------- K0: ALL prepasses (block-range dispatch) ----------------
// blk [0,448):      Wall hi/lo + bias448
// blk [448,1600):   Wb conv-weight pack
// blk [1600,1860):  msP halo zero
// blk [1860,5956):  msP interior (ms -> padded bf16 hi, transposed)
__global__ __launch_bounds__(256) void k0(
    const float* __restrict__ Wc_w, const float* __restrict__ Wc_b,
    const float* __restrict__ Wf_w, const float* __restrict__ Wf_b,
    const float* __restrict__ Wk_w, const float* __restrict__ Wk_b,
    const float* __restrict__ Wv, const float* __restrict__ ms,
    unsigned short* __restrict__ Wall, unsigned short* __restrict__ Wallo,
    float* __restrict__ bias448, unsigned short* __restrict__ Wb,
    unsigned short* __restrict__ msP) {
    __shared__ float Ls[32][65];
    int blk = blockIdx.x;
    int t = threadIdx.x;
    if (blk < 448) {
        int o = blk * 256 + t;                    // 114688
        int ci8 = o & 7;
        int idx = o >> 3;                         // sc4*448 + row
        int row = idx % 448;
        int sc4 = idx / 448;                      // s*4 + c4
        int f = (sc4 >> 2) * 32 + (sc4 & 3) * 8 + ci8;
        float w;
        if (row < 128) {
            float s = 0.f;
            for (int o2 = 0; o2 < 128; ++o2) s += Wc_w[o2 * 128 + row] * Wf_w[o2 * 256 + f];
            w = s;
        } else if (row < 384) {
            int p = (row - 128) >> 1;
            w = (row & 1) ? Wk_w[p * 256 + f] : Wf_w[p * 256 + f];
        } else if (row == 384) {
            float s = 0.f;
            for (int o2 = 0; o2 < 128; ++o2) s += Wc_b[o2] * Wf_w[o2 * 256 + f];
            w = s;
        } else w = 0.f;
        unsigned short hi = f2b(w);
        Wall[o] = hi;
        Wallo[o] = f2b(w - b2f(hi));
        if (o < 448) {
            float bb;
            if (o < 128) {
                float s = 0.f;
                for (int o2 = 0; o2 < 128; ++o2) s += Wc_w[o2 * 128 + o] * Wf_b[o2];
                bb = s;
            } else if (o < 384) {
                int p = (o - 128) >> 1;
                bb = (o & 1) ? Wk_b[p] : Wf_b[p];
            } else if (o == 384) {
                float s = 0.f;
                for (int o2 = 0; o2 < 128; ++o2) s += Wc_b[o2] * Wf_b[o2];
                bb = s;
            } else if (o == 385) bb = -1.f;
            else bb = 0.f;
            bias448[o] = bb;
        }
    } else if (blk < 1600) {
        int o = (blk - 448) * 256 + t;            // 294912
        int ci8 = o & 7;
        int co  = (o >> 3) & 127;
        int c4  = (o >> 10) & 3;
        int s   = (o >> 12) & 7;
        int khw = o >> 15;                        // [0,9)
        int ci  = s * 32 + c4 * 8 + ci8;
        int kh  = khw / 3, kw = khw - kh * 3;
        Wb[o] = f2b(Wv[((co * 256 + ci) * 3 + kh) * 3 + kw]);
    } else if (blk < 1860) {
        int i = (blk - 1600) * 256 + t;           // 66560 exactly
        if (i < 66560) {
            size_t off;
            if (i < 33792) {          // rows y=0,65
                int x = i % 66; int r = i / 66;
                int g = r & 31, rowi = (r >> 5) & 1, b = r >> 6;
                off = ((((size_t)b * 66 + rowi * 65) * 32) + g) * 66 + x;
            } else {                  // cols x=0,65 for y=1..64
                int k = i - 33792;
                int xi = k & 1; int g = (k >> 1) & 31; int y1 = (k >> 6) & 63; int b = k >> 12;
                off = ((((size_t)b * 66 + (y1 + 1)) * 32) + g) * 66 + xi * 65;
            }
            *(u16x8*)&msP[off * 8] = (u16x8){0, 0, 0, 0, 0, 0, 0, 0};
        }
    } else {
        int local = blk - 1860;        // 4096 = 8b * 64h * 8s
        int s = local & 7;
        int h = (local >> 3) & 63;
        int b = local >> 9;
        const float* src = ms + ((size_t)b * 256 + s * 32) * HW + h * 64;
        for (int l = t; l < 2048; l += 256) {
            int ci = l >> 6, w = l & 63;
            Ls[ci][w] = src[ci * HW + w];
        }
        __syncthreads();
        int w = t & 63, gi = t >> 6;   // gi in [0,4)
        u16x8 vh;
#pragma unroll
        for (int j = 0; j < 8; ++j) vh[j] = f2b(Ls[gi * 8 + j][w]);
        size_t offH = ((((size_t)b * 66 + (h + 1)) * 32) + (s * 4 + gi)) * 66 + (w + 1);
        *(u16x8*)&msP[offH * 8] = vh;
    }
}

// ---------------- KMM: fused k1m (qt/q/mkey/lm) + k2m (3x3 conv) ----------------
// grid 1024, block 512 (8 waves):
//   blk [0,512):    k1m — b=blk>>6, h=blk&63; wm=wid>>1 (112 rows), wn=wid&1 (x-half)
//                   input staged from fp32 ms in registers -> hi/lo bf16 LDS planes
//   blk [512,1024): k2m — h XCD-chunk-swizzled; wm=wid>>1 (32 co), wn=wid&1 (x-half)
__global__ __launch_bounds__(512, 4) void kmm(
    const float* __restrict__ ms, const unsigned short* __restrict__ msP,
    const unsigned short* __restrict__ Wall, const unsigned short* __restrict__ Wallo,
    const float* __restrict__ bias448, const unsigned short* __restrict__ Wb,
    const float* __restrict__ Wv_b,
    float* __restrict__ qt, float* __restrict__ lm, float* __restrict__ vals) {
    __shared__ unsigned char smem[25856] __attribute__((aligned(16)));
    int t = threadIdx.x;
    int lane = t & 63, wid = t >> 6;
    int c4l = lane >> 4, lrow = lane & 15;
    int blk = blockIdx.x;

    if (blk < 512) {
        // ================= k1m part =================
        auto Bs = (unsigned short (*)[2][4][64][8])smem;   // [buf][plane][c4][x][ci8]
        float* biasS = (float*)(smem + 16384);
        float* lmAcc = (float*)(smem + 16384 + 1792);
        int wm = wid >> 1, wn = wid & 1;
        int b = blk >> 6, h = blk & 63;
        int xs = t & 63, g4 = t >> 6;              // stage role: x, 4-ci group
        int c4w = g4 >> 1, sub = g4 & 1;
        const float* msb = ms + ((size_t)b * 256 + g4 * 4) * HW + h * 64 + xs;
        for (int i = t; i < 448; i += 512) biasS[i] = bias448[i];
        if (t < 64) lmAcc[t] = 0.f;

        f32x4 acc[7][2];
#pragma unroll
        for (int mf = 0; mf < 7; ++mf)
#pragma unroll
            for (int nf = 0; nf < 2; ++nf) acc[mf][nf] = (f32x4){0.f, 0.f, 0.f, 0.f};

        const bf16x8* Whip = (const bf16x8*)Wall;
        const bf16x8* Wlop = (const bf16x8*)Wallo;

#define CVT_WRITE(bufv, F0, F1, F2, F3) do {                                    \
        unsigned short h0 = f2b(F0), h1 = f2b(F1), h2 = f2b(F2), h3 = f2b(F3);  \
        unsigned short q0 = f2b((F0) - b2f(h0)), q1 = f2b((F1) - b2f(h1));      \
        unsigned short q2 = f2b((F2) - b2f(h2)), q3 = f2b((F3) - b2f(h3));      \
        uint2 hw, lw;                                                           \
        hw.x = (unsigned)h0 | ((unsigned)h1 << 16);                             \
        hw.y = (unsigned)h2 | ((unsigned)h3 << 16);                             \
        lw.x = (unsigned)q0 | ((unsigned)q1 << 16);                             \
        lw.y = (unsigned)q2 | ((unsigned)q3 << 16);                             \
        *(uint2*)&Bs[bufv][0][c4w][xs][sub * 4] = hw;                           \
        *(uint2*)&Bs[bufv][1][c4w][xs][sub * 4] = lw;                           \
    } while (0)

        {   // prologue: stage s=0 into buf0
            float f0 = msb[0], f1 = msb[HW], f2 = msb[2 * HW], f3 = msb[3 * HW];
            CVT_WRITE(0, f0, f1, f2, f3);
        }
        __syncthreads();

        for (int s = 0; s < 8; ++s) {
            int cur = s & 1;
            float fn0, fn1, fn2, fn3;
            if (s < 7) {   // issue next-step loads early (latency hides under MFMA)
                const float* p = msb + (size_t)(s + 1) * 32 * HW;
                fn0 = p[0]; fn1 = p[HW]; fn2 = p[2 * HW]; fn3 = p[3 * HW];
            }
            bf16x8 bh[2], bl[2];
#pragma unroll
            for (int nf = 0; nf < 2; ++nf) {
                int x = wn * 32 + nf * 16 + lrow;
                bh[nf] = *(const bf16x8*)&Bs[cur][0][c4l][x][0];
                bl[nf] = *(const bf16x8*)&Bs[cur][1][c4l][x][0];
            }
#pragma unroll
            for (int mf = 0; mf < 7; ++mf) {
                size_t widx = (size_t)(s * 4 + c4l) * 448 + wm * 112 + mf * 16 + lrow;
                bf16x8 ah = Whip[widx];
                bf16x8 al = Wlop[widx];
#pragma unroll
                for (int nf = 0; nf < 2; ++nf) {
                    acc[mf][nf] = __builtin_amdgcn_mfma_f32_16x16x32_bf16(ah, bh[nf], acc[mf][nf], 0, 0, 0);
                    acc[mf][nf] = __builtin_amdgcn_mfma_f32_16x16x32_bf16(ah, bl[nf], acc[mf][nf], 0, 0, 0);
                    acc[mf][nf] = __builtin_amdgcn_mfma_f32_16x16x32_bf16(al, bh[nf], acc[mf][nf], 0, 0, 0);
                }
            }
            if (s < 7) CVT_WRITE(cur ^ 1, fn0, fn1, fn2, fn3);
            __syncthreads();
        }
#undef CVT_WRITE

        // epilogue: D layout col=lane&15 (px), row=(lane>>4)*4+j
        int px0 = wn * 32;
        float lmp[2] = {0.f, 0.f};
#pragma unroll
        for (int mf = 0; mf < 7; ++mf) {
            int base = wm * 112 + mf * 16;
            int r0 = base + c4l * 4;
            if (base < 128) {
#pragma unroll
                for (int nf = 0; nf < 2; ++nf) {
                    int x = px0 + nf * 16 + lrow;
                    float* dst = qt + ((size_t)b * 128 + r0) * HW + h * 64 + x;
                    f32x4 v = acc[mf][nf];
#pragma unroll
                    for (int j = 0; j < 4; ++j)
                        dst[(size_t)j * HW] = v[j] + biasS[r0 + j];
                }
            } else {
                float b0 = biasS[r0], b1 = biasS[r0 + 1], b2 = biasS[r0 + 2], b3 = biasS[r0 + 3];
#pragma unroll
                for (int nf = 0; nf < 2; ++nf) {
                    f32x4 v = acc[mf][nf];
                    lmp[nf] += (v[0] + b0) * (v[1] + b1) + (v[2] + b2) * (v[3] + b3);
                }
            }
        }
        if (wm != 0) {
#pragma unroll
            for (int nf = 0; nf < 2; ++nf) {
                lmp[nf] += __shfl_xor(lmp[nf], 16);
                lmp[nf] += __shfl_xor(lmp[nf], 32);
            }
            if (c4l == 0) {
#pragma unroll
                for (int nf = 0; nf < 2; ++nf)
                    atomicAdd(&lmAcc[px0 + nf * 16 + lrow], lmp[nf]);
            }
        }
        __syncthreads();
        if (t < 64) lm[b * HW + h * 64 + t] = lmAcc[t];
    } else {
        // ================= k2m part =================
        auto Bs = (unsigned short (*)[6336])smem;          // [buf][792 chunks * 8]
        float* biasS = (float*)(smem + 25344);
        int local = blk - 512;
        int b = local >> 6;
        int hl = local & 63;
        int h = ((hl & 7) << 3) | (hl >> 3);   // XCD h-chunking (bijective 3-bit swap)
        int wm = wid >> 1, wn = wid & 1;
        if (t < 128) biasS[t] = Wv_b[t];

        f32x4 acc[2][2];
#pragma unroll
        for (int mf = 0; mf < 2; ++mf)
#pragma unroll
            for (int nf = 0; nf < 2; ++nf) acc[mf][nf] = (f32x4){0.f, 0.f, 0.f, 0.f};

        const bf16x8* Wbp = (const bf16x8*)Wb;

#define STAGE2(bufv, sv) do {                                                       \
        for (int iter = 0; iter < 2; ++iter) {                                      \
            int q0 = iter * 512 + (wid << 6);                                       \
            int q = q0 + lane;                                                      \
            if (q < 792) {                                                          \
                int rc = q / 66; int x = q - rc * 66;                               \
                int r = rc >> 2, c4 = rc & 3;                                       \
                int y = h + r;                      /* msP rows h-1..h+1 */         \
                const unsigned short* gp = msP +                                    \
                    (((((size_t)b * 66 + y) * 32) + ((sv) * 4 + c4)) * 66 + x) * 8; \
                unsigned short* lp = &Bs[bufv][q0 * 8];                             \
                __builtin_amdgcn_global_load_lds(                                   \
                    (const __attribute__((address_space(1))) void*)gp,              \
                    (__attribute__((address_space(3))) void*)lp, 16, 0, 0);         \
            }                                                                       \
        }                                                                           \
    } while (0)

        STAGE2(0, 0);
        __syncthreads();

        for (int s = 0; s < 8; ++s) {
            int cur = s & 1;
            if (s < 7) STAGE2(cur ^ 1, s + 1);
#pragma unroll
            for (int khw = 0; khw < 9; ++khw) {
                int kh = khw / 3, kw = khw - 3 * (khw / 3);
                bf16x8 a[2];
#pragma unroll
                for (int mf = 0; mf < 2; ++mf)
                    a[mf] = Wbp[((khw * 8 + s) * 4 + c4l) * 128 + wm * 32 + mf * 16 + lrow];
                bf16x8 bf[2];
#pragma unroll
                for (int nf = 0; nf < 2; ++nf) {
                    int chunk = (kh * 4 + c4l) * 66 + wn * 32 + nf * 16 + lrow + kw;
                    bf[nf] = *(const bf16x8*)&Bs[cur][chunk * 8];
                }
#pragma unroll
                for (int mf = 0; mf < 2; ++mf)
#pragma unroll
                    for (int nf = 0; nf < 2; ++nf)
                        acc[mf][nf] = __builtin_amdgcn_mfma_f32_16x16x32_bf16(
                            a[mf], bf[nf], acc[mf][nf], 0, 0, 0);
            }
            __syncthreads();
        }
#undef STAGE2

        // epilogue: D layout col=lane&15 (px), row=(lane>>4)*4+j (co)
#pragma unroll
        for (int mf = 0; mf < 2; ++mf) {
            int co0 = wm * 32 + mf * 16 + c4l * 4;
#pragma unroll
            for (int nf = 0; nf < 2; ++nf) {
                int x = wn * 32 + nf * 16 + lrow;
                float* dst = vals + (((size_t)b * 128 + co0) * HW) + h * 64 + x;
                f32x4 v = acc[mf][nf];
#pragma unroll
                for (int j = 0; j < 4; ++j)
                    dst[(size_t)j * HW] = v[j] + biasS[co0 + j];
            }
        }
    }
}

// ---------------- K3: register-resident logits -> softmax -> combine ----------------
// grid 2048 = b(8) x y(128) x xh(2); block 256: xg = t&15 (4x each), cq = t>>4 (8c each)
__global__ __launch_bounds__(256, 2) void k3(
    const float* __restrict__ ctx, const float* __restrict__ qt,
    const float* __restrict__ vals, const float* __restrict__ lm,
    float* __restrict__ out) {
    __shared__ float part[4][3][64];
    __shared__ float attnS[4][64];
    int t = threadIdx.x;
    int lane = t & 63, wv = t >> 6;
    int xg = t & 15, cq = t >> 4;
    int blk = blockIdx.x;
    int b = blk >> 8, y = (blk >> 1) & 127, xh = blk & 1;
    int h = y >> 1;
    int x0 = xh * 64 + xg * 4;
    int p0 = xh * 32 + xg * 2;

    float2 qv[8], vv[8];
    const float* qbase = qt + ((size_t)b * 128 + cq * 8) * HW + h * 64 + p0;
    const float* vbase = vals + ((size_t)b * 128 + cq * 8) * HW + h * 64 + p0;
#pragma unroll
    for (int j = 0; j < 8; ++j) {
        qv[j] = *(const float2*)&qbase[(size_t)j * HW];
        vv[j] = *(const float2*)&vbase[(size_t)j * HW];
    }
    float4 cx[3][8];
#pragma unroll
    for (int n = 0; n < 3; ++n) {
        const float* cb = ctx + ((size_t)(n * 8 + b) * 128 + cq * 8) * YX + (size_t)y * 128 + x0;
#pragma unroll
        for (int j = 0; j < 8; ++j) cx[n][j] = *(const float4*)&cb[(size_t)j * YX];
    }
    float lp[3][4];
#pragma unroll
    for (int n = 0; n < 3; ++n) {
#pragma unroll
        for (int xl = 0; xl < 4; ++xl) lp[n][xl] = 0.f;
#pragma unroll
        for (int j = 0; j < 8; ++j) {
            lp[n][0] += cx[n][j].x * qv[j].x;
            lp[n][1] += cx[n][j].y * qv[j].x;
            lp[n][2] += cx[n][j].z * qv[j].y;
            lp[n][3] += cx[n][j].w * qv[j].y;
        }
    }
#pragma unroll
    for (int n = 0; n < 3; ++n)
#pragma unroll
        for (int xl = 0; xl < 4; ++xl) {
            float v = lp[n][xl];
            v += __shfl_xor(v, 16);
            v += __shfl_xor(v, 32);
            lp[n][xl] = v;
        }
    if (lane < 16) {
#pragma unroll
        for (int n = 0; n < 3; ++n)
#pragma unroll
            for (int xl = 0; xl < 4; ++xl)
                part[wv][n][lane * 4 + xl] = lp[n][xl];
    }
    __syncthreads();
    if (t < 64) {
        float l0 = part[0][0][t] + part[1][0][t] + part[2][0][t] + part[3][0][t];
        float l1 = part[0][1][t] + part[1][1][t] + part[2][1][t] + part[3][1][t];
        float l2 = part[0][2][t] + part[1][2][t] + part[2][2][t] + part[3][2][t];
        float l3 = lm[(size_t)b * HW + h * 64 + xh * 32 + (t >> 1)];
        float m = fmaxf(fmaxf(l0, l1), fmaxf(l2, l3));
        float e0 = __expf(l0 - m), e1 = __expf(l1 - m), e2 = __expf(l2 - m), e3 = __expf(l3 - m);
        float inv = 1.f / (e0 + e1 + e2 + e3);
        attnS[0][t] = e0 * inv; attnS[1][t] = e1 * inv;
        attnS[2][t] = e2 * inv; attnS[3][t] = e3 * inv;
    }
    __syncthreads();
    float a0[4], a1[4], a2[4], a3[4];
#pragma unroll
    for (int xl = 0; xl < 4; ++xl) {
        a0[xl] = attnS[0][xg * 4 + xl];
        a1[xl] = attnS[1][xg * 4 + xl];
        a2[xl] = attnS[2][xg * 4 + xl];
        a3[xl] = attnS[3][xg * 4 + xl];
    }
    float* obase = out + ((size_t)b * 128 + cq * 8) * YX + (size_t)y * 128 + x0;
#pragma unroll
    for (int j = 0; j < 8; ++j) {
        float4 o;
        o.x = a3[0] * vv[j].x + a0[0] * cx[0][j].x + a1[0] * cx[1][j].x + a2[0] * cx[2][j].x;
        o.y = a3[1] * vv[j].x + a0[1] * cx[0][j].y + a1[1] * cx[1][j].y + a2[1] * cx[2][j].y;
        o.z = a3[2] * vv[j].y + a0[2] * cx[0][j].z + a1[2] * cx[1][j].z + a2[2] * cx[2][j].z;
        o.w = a3[3] * vv[j].y + a0[3] * cx[0][j].w + a1[3] * cx[1][j].w + a2[3] * cx[2][j].w;
        *(float4*)&obase[(size_t)j * YX] = o;
    }
}

extern "C" void kernel_launch(void* const* d_in, const int* in_sizes, int n_in,
                              void* d_out, int out_size, void* d_ws, size_t ws_size,
                              hipStream_t stream) {
    const float* ctx  = (const float*)d_in[0];
    const float* ms   = (const float*)d_in[1];
    const float* Wc_w = (const float*)d_in[2];
    const float* Wc_b = (const float*)d_in[3];
    const float* Wf_w = (const float*)d_in[4];
    const float* Wf_b = (const float*)d_in[5];
    const float* Wk_w = (const float*)d_in[6];
    const float* Wk_b = (const float*)d_in[7];
    const float* Wv_w = (const float*)d_in[8];
    const float* Wv_b = (const float*)d_in[9];
    float* out = (float*)d_out;
    float* ws = (float*)d_ws;
    float* qt      = ws + WS_QT;
    float* vals    = ws + WS_VALS;
    float* bias448 = ws + WS_BIAS;
    float* lmp     = ws + WS_LM;
    unsigned short* Wallp  = (unsigned short*)(ws + WS_WALL);
    unsigned short* Wallop = (unsigned short*)(ws + WS_WALLO);
    unsigned short* msPp   = (unsigned short*)(ws + WS_MSP);
    unsigned short* Wbp    = (unsigned short*)(ws + WS_WB);

    hipLaunchKernelGGL(k0, dim3(5956), dim3(256), 0, stream, Wc_w, Wc_b, Wf_w, Wf_b,
                       Wk_w, Wk_b, Wv_w, ms, Wallp, Wallop, bias448, Wbp, msPp);
    hipLaunchKernelGGL(kmm, dim3(1024), dim3(512), 0, stream, ms, msPp, Wallp, Wallop,
                       bias448, Wbp, Wv_b, qt, lmp, vals);
    hipLaunchKernelGGL(k3, dim3(2048), dim3(256), 0, stream, ctx, qt, vals, lmp, out);
}